// Round 14
// baseline (292.949 us; speedup 1.0000x reference)
//
#include <hip/hip_runtime.h>
#include <stdint.h>

#define NB 32
#define NS 40
#define NT 60
#define NH 256
#define NF 64
#define NDIN 320
#define NG 1024
#define NSB 1280
#define NOUT 128

typedef __bf16 bf16x8 __attribute__((ext_vector_type(8)));
typedef float f32x4 __attribute__((ext_vector_type(4)));
typedef uint32_t u32x4 __attribute__((ext_vector_type(4)));

union bfrag { bf16x8 v; uint16_t u[8]; uint4 q; uint64_t d[2]; };
union f2arr { float2 v; float a[2]; };

__device__ __forceinline__ uint16_t f2bf(float f) {
  uint32_t u = __float_as_uint(f);
  u += 0x7fffu + ((u >> 16) & 1u);
  return (uint16_t)(u >> 16);
}
__device__ __forceinline__ float bf2f(uint16_t h) {
  return __uint_as_float(((uint32_t)h) << 16);
}
__device__ __forceinline__ float sig_fast(float x) { return 1.0f / (1.0f + __expf(-x)); }
__device__ __forceinline__ float tanh_fast(float x) {
  x = fminf(fmaxf(x, -15.0f), 15.0f);
  float t = __expf(2.0f * x);
  return (t - 1.0f) / (t + 1.0f);
}
__device__ __forceinline__ uint32_t ld_agent_u32(const uint32_t* p) {
  return __hip_atomic_load(p, __ATOMIC_RELAXED, __HIP_MEMORY_SCOPE_AGENT);
}
__device__ __forceinline__ int ld_agent_int(const int* p) {
  return __hip_atomic_load(p, __ATOMIC_RELAXED, __HIP_MEMORY_SCOPE_AGENT);
}
__device__ __forceinline__ void st_agent_f32(float* p, float v) {
  __hip_atomic_store((uint32_t*)p, __float_as_uint(v), __ATOMIC_RELAXED, __HIP_MEMORY_SCOPE_AGENT);
}
__device__ __forceinline__ float2 lda_f2(const float* p) {
  union { uint64_t u; float2 f; } c;
  c.u = __hip_atomic_load((const uint64_t*)p, __ATOMIC_RELAXED, __HIP_MEMORY_SCOPE_AGENT);
  return c.f;
}

// ------- detect (32 blocks): classify mask dtype into per-block slots AND
// zero granules + strip tags (replaces hipMemsetAsync).
__global__ __launch_bounds__(256) void k_detect(const uint32_t* __restrict__ xm,
                                                int* __restrict__ ctrl,
                                                uint32_t* __restrict__ gr) {
  int bid = blockIdx.x, tid = threadIdx.x;
  {
    int gidx = bid * 256 + tid;
    u32x4 z = {0, 0, 0, 0};
    asm volatile("global_store_dwordx4 %0, %1, off sc1"
                 :: "v"((unsigned long long)(uintptr_t)(gr + (size_t)gidx * 4)), "v"(z)
                 : "memory");
  }
  if (bid == 0 && tid < 64) ctrl[64 + tid] = 0;   // strip tags
  __shared__ int s_notint, s_notflt;
  if (tid == 0) { s_notint = 0; s_notflt = 0; }
  __syncthreads();
  int notint = 0, notflt = 0;
  for (int i = bid * 600 + tid; i < (bid + 1) * 600; i += 256) {  // 32*600 = 19200 u32
    uint32_t v = xm[i];
    if (v > 1u) notint = 1;
    if (v != 0u && v != 0x3f800000u) notflt = 1;
  }
  if (notint) atomicOr(&s_notint, 1);
  if (notflt) atomicOr(&s_notflt, 1);
  __syncthreads();
  if (tid == 0) ctrl[8 + bid] = s_notint | (s_notflt << 1);
}

// ------- merged: blocks [0,1280) attention pooling; [1280,2560) wih prep ----
__global__ __launch_bounds__(256) void k_attn_prep(
    const int* __restrict__ x, const void* __restrict__ xmask,
    const float* __restrict__ xfeat, const int* __restrict__ slen,
    const float* __restrict__ emb, const float* __restrict__ attn_w,
    uint16_t* __restrict__ Xb, const int* __restrict__ flagp,
    const float* __restrict__ wf, const float* __restrict__ wb,
    uint16_t* __restrict__ outw)
{
  int tid = threadIdx.x;
  if (blockIdx.x >= 1280) {              // ---- wih -> hi/lo bf16 planes ----
    const int n = NG * NDIN;
    for (int idx = (blockIdx.x - 1280) * 256 + tid; idx < 2 * n; idx += 1280 * 256) {
      float v = (idx < n) ? wf[idx] : wb[idx - n];
      uint16_t hi = f2bf(v);
      outw[idx] = hi;
      outw[2 * n + idx] = f2bf(v - bf2f(hi));
    }
    return;
  }
  int bs = blockIdx.x;
  int b = bs / NS, s = bs % NS;
  uint16_t* Xh = Xb + (size_t)(s * NB + b) * NDIN;
  uint16_t* Xl = Xh + (size_t)NSB * NDIN;
  int len = slen[b];
  if (s >= len) {
    for (int i = tid; i < NDIN; i += 256) { Xh[i] = 0; Xl[i] = 0; }
    return;
  }
  __shared__ __attribute__((aligned(16))) float sw[NH];
  __shared__ float salpha[NT];
  __shared__ int sidx[NT];
  __shared__ unsigned char svalid[NT];
  __shared__ __attribute__((aligned(16))) uint16_t es[NT][NH];
  sw[tid] = attn_w[tid];
  int nv = 0;
  #pragma unroll
  for (int q = 0; q < 32; q++) nv |= flagp[8 + q];
  int flag = (!(nv & 1)) ? 0 : ((!(nv & 2)) ? 2 : 1);
  if (tid < NT) {
    int mi = bs * NT + tid;
    sidx[tid] = x[mi];
    int mv;
    if (flag == 1)      mv = ((const unsigned char*)xmask)[mi];
    else if (flag == 2) mv = (((const float*)xmask)[mi] != 0.0f) ? 1 : 0;
    else                mv = ((const int*)xmask)[mi];
    svalid[tid] = (mv == 0) ? 1 : 0;
  }
  __syncthreads();
  int wave = tid >> 6, lane = tid & 63;
  for (int t = wave; t < NT; t += 4) {
    float d = 0.0f;
    if (svalid[t]) {
      const float* er = emb + (size_t)sidx[t] * NH;
      float4 e4 = ((const float4*)er)[lane];
      float4 w4 = ((const float4*)sw)[lane];
      uint16_t* ed = &es[t][lane * 4];
      ed[0] = f2bf(e4.x); ed[1] = f2bf(e4.y); ed[2] = f2bf(e4.z); ed[3] = f2bf(e4.w);
      d = e4.x * w4.x + e4.y * w4.y + e4.z * w4.z + e4.w * w4.w;
      #pragma unroll
      for (int o = 32; o > 0; o >>= 1) d += __shfl_down(d, o);
    }
    if (lane == 0) salpha[t] = d;
  }
  __syncthreads();
  if (tid < 64) {                        // wave-parallel softmax over <=60 tokens
    int valid = (tid < NT) && svalid[tid];
    float v = valid ? salpha[tid] : -1e30f;
    float m = v;
    #pragma unroll
    for (int o = 32; o > 0; o >>= 1) m = fmaxf(m, __shfl_xor(m, o));
    float e = valid ? expf(v - m) : 0.0f;
    float ssum = e;
    #pragma unroll
    for (int o = 32; o > 0; o >>= 1) ssum += __shfl_xor(ssum, o);
    if (tid < NT) salpha[tid] = e / ssum;
  }
  __syncthreads();
  float acc = 0.0f;
  for (int t = 0; t < NT; t++) {
    float a = salpha[t];
    if (a != 0.0f) acc += a * bf2f(es[t][tid]);
  }
  {
    uint16_t hi = f2bf(acc);
    Xh[tid] = hi; Xl[tid] = f2bf(acc - bf2f(hi));
  }
  if (tid < NF) {
    float fa = 0.0f;
    const float* fp = xfeat + (size_t)bs * NT * NF + tid;
    for (int t = 0; t < NT; t++) if (svalid[t]) fa += fp[t * NF];
    uint16_t hi = f2bf(fa);
    Xh[NH + tid] = hi; Xl[NH + tid] = f2bf(fa - bf2f(hi));
  }
}

// ---- fused: blocks [16,336) gbase (strip-tagged); blocks [0,16) LSTM+final --
__global__ __launch_bounds__(512, 2) void k_fused(
    const uint16_t* __restrict__ Xb, const uint16_t* __restrict__ wihb,
    const float* __restrict__ bih_f, const float* __restrict__ bhh_f,
    const float* __restrict__ bih_b, const float* __restrict__ bhh_b,
    const float* __restrict__ whh_f_, const float* __restrict__ whh_b_,
    const int* __restrict__ slen, float* __restrict__ gbase,
    uint32_t* __restrict__ gr, int* __restrict__ ctrl,
    const float* __restrict__ fc_w, const float* __restrict__ fc_b,
    const float* __restrict__ gamma_, const float* __restrict__ beta_,
    float* __restrict__ outp)
{
  __shared__ __attribute__((aligned(16))) char smem_[65664];
  int tid = threadIdx.x, wave = tid >> 6, lane = tid & 63;
  int lrow = lane & 15, lkb = (lane >> 4) * 8;

  if (blockIdx.x >= 16) {
    // ================= gbase branch (320 blocks, 2560 wave-jobs) ===========
    const int n = NG * NDIN;
    int job = (blockIdx.x - 16) * 8 + wave;
    int dir = job / 1280;
    int r = job % 1280;
    int nt = r % 64, ms = r / 64;
    int m0 = ms * 64;
    const uint16_t* Wh = wihb + (size_t)dir * n;
    const uint16_t* Wl = Wh + (size_t)2 * n;
    const uint16_t* Ah = Xb;
    const uint16_t* Al = Xb + (size_t)NSB * NDIN;
    int lk = lkb;
    f32x4 acc0 = {0,0,0,0}, acc1 = acc0, acc2 = acc0, acc3 = acc0;
    for (int kk = 0; kk < 10; kk++) {
      int k0 = kk * 32 + lk;
      bfrag bh, bl, ah0, ah1, ah2, ah3, al0, al1, al2, al3;
      bh.q = *(const uint4*)(Wh + (size_t)(nt * 16 + lrow) * NDIN + k0);
      bl.q = *(const uint4*)(Wl + (size_t)(nt * 16 + lrow) * NDIN + k0);
      ah0.q = *(const uint4*)(Ah + (size_t)(m0 +  0 + lrow) * NDIN + k0);
      ah1.q = *(const uint4*)(Ah + (size_t)(m0 + 16 + lrow) * NDIN + k0);
      ah2.q = *(const uint4*)(Ah + (size_t)(m0 + 32 + lrow) * NDIN + k0);
      ah3.q = *(const uint4*)(Ah + (size_t)(m0 + 48 + lrow) * NDIN + k0);
      al0.q = *(const uint4*)(Al + (size_t)(m0 +  0 + lrow) * NDIN + k0);
      al1.q = *(const uint4*)(Al + (size_t)(m0 + 16 + lrow) * NDIN + k0);
      al2.q = *(const uint4*)(Al + (size_t)(m0 + 32 + lrow) * NDIN + k0);
      al3.q = *(const uint4*)(Al + (size_t)(m0 + 48 + lrow) * NDIN + k0);
      acc0 = __builtin_amdgcn_mfma_f32_16x16x32_bf16(ah0.v, bh.v, acc0, 0, 0, 0);
      acc0 = __builtin_amdgcn_mfma_f32_16x16x32_bf16(ah0.v, bl.v, acc0, 0, 0, 0);
      acc0 = __builtin_amdgcn_mfma_f32_16x16x32_bf16(al0.v, bh.v, acc0, 0, 0, 0);
      acc1 = __builtin_amdgcn_mfma_f32_16x16x32_bf16(ah1.v, bh.v, acc1, 0, 0, 0);
      acc1 = __builtin_amdgcn_mfma_f32_16x16x32_bf16(ah1.v, bl.v, acc1, 0, 0, 0);
      acc1 = __builtin_amdgcn_mfma_f32_16x16x32_bf16(al1.v, bh.v, acc1, 0, 0, 0);
      acc2 = __builtin_amdgcn_mfma_f32_16x16x32_bf16(ah2.v, bh.v, acc2, 0, 0, 0);
      acc2 = __builtin_amdgcn_mfma_f32_16x16x32_bf16(ah2.v, bl.v, acc2, 0, 0, 0);
      acc2 = __builtin_amdgcn_mfma_f32_16x16x32_bf16(al2.v, bh.v, acc2, 0, 0, 0);
      acc3 = __builtin_amdgcn_mfma_f32_16x16x32_bf16(ah3.v, bh.v, acc3, 0, 0, 0);
      acc3 = __builtin_amdgcn_mfma_f32_16x16x32_bf16(ah3.v, bl.v, acc3, 0, 0, 0);
      acc3 = __builtin_amdgcn_mfma_f32_16x16x32_bf16(al3.v, bh.v, acc3, 0, 0, 0);
    }
    int col = nt * 16 + lrow;
    float bias = dir ? (bih_b[col] + bhh_b[col]) : (bih_f[col] + bhh_f[col]);
    float* gb = gbase + (size_t)dir * NSB * NG;
    int rb = (lane >> 4) * 4;
    #pragma unroll
    for (int rr = 0; rr < 4; rr++) {
      st_agent_f32(&gb[(size_t)(m0 +  0 + rb + rr) * NG + col], acc0[rr] + bias);
      st_agent_f32(&gb[(size_t)(m0 + 16 + rb + rr) * NG + col], acc1[rr] + bias);
      st_agent_f32(&gb[(size_t)(m0 + 32 + rb + rr) * NG + col], acc2[rr] + bias);
      st_agent_f32(&gb[(size_t)(m0 + 48 + rb + rr) * NG + col], acc3[rr] + bias);
    }
    asm volatile("s_waitcnt vmcnt(0)" ::: "memory");
    if (lane == 0)
      __hip_atomic_fetch_add(&ctrl[64 + dir * 32 + ms], 1,
                             __ATOMIC_RELAXED, __HIP_MEMORY_SCOPE_AGENT);
    return;
  }

  // ================= LSTM branch (16 blocks) + final epilogue ==============
  int wg = blockIdx.x;
  int dir = wg >> 3, p = wg & 7;
  int u0 = p * 32;
  const float* Wr = dir ? whh_b_ : whh_f_;
  const float* gb = gbase + (size_t)dir * NSB * NG;
  uint32_t* grd = gr + (size_t)dir * 2 * 64 * NB * 4;   // [par][g64][batch]{4xu32}
  uint16_t (*hs)[264] = (uint16_t(*)[264])smem_;
  volatile float* ts = (volatile float*)(smem_ + 16896) + wave * 576;

  bfrag wh[8];
  {
    int wr = (lrow >> 2) * 256 + u0 + wave * 4 + (lrow & 3);
    const float* wrow = Wr + (size_t)wr * NH;
    #pragma unroll
    for (int kk = 0; kk < 8; kk++) {
      int k0 = kk * 32 + lkb;
      bfrag th;
      #pragma unroll
      for (int e = 0; e < 8; e++) th.u[e] = f2bf(wrow[k0 + e]);
      wh[kk] = th;
    }
  }
  int beta = lane >> 1;
  int g64 = p * 8 + wave;
  int len = slen[beta];
  uint32_t hprev_hi = 0;
  float c0 = 0.0f, c1 = 0.0f;

  unsigned long long sa[2][4];
  #pragma unroll
  for (int par = 0; par < 2; par++) {
    const uint32_t* gpar = grd + (size_t)par * 64 * NB * 4;
    #pragma unroll
    for (int q = 0; q < 4; q++)
      sa[par][q] = (unsigned long long)(uintptr_t)(gpar + (size_t)(tid + q * 512) * 4);
  }

  // prologue: wait for first gbase strip, load g(t0)
  uint32_t ready_mask = 0;
  f2arr g0, g1, g2, g3;
  {
    int t0 = dir ? (NS - 1) : 0;
    int ms0 = t0 >> 1;
    long sp = 0;
    while (ld_agent_int(&ctrl[64 + dir * 32 + ms0]) < 64) {
      __builtin_amdgcn_s_sleep(2);
      if (++sp > (1L << 20)) break;
    }
    ready_mask |= 1u << ms0;
    const float* gptr = gb + ((size_t)t0 * NB + beta) * NG + u0 + wave * 4 + (lane & 1) * 2;
    g0.v = lda_f2(gptr);       g1.v = lda_f2(gptr + 256);
    g2.v = lda_f2(gptr + 512); g3.v = lda_f2(gptr + 768);
  }

  for (int i = 0; i < NS; i++) {
    int t = dir ? (NS - 1 - i) : i;
    // ---- tagged-granule fetch: 4 x 16B sc1, retry until tags >= i ----
    u32x4 v0, v1, v2, v3;
    {
      const unsigned long long* a = sa[i & 1];
      uint32_t need = (uint32_t)i;
      long spins = 0;
      for (;;) {
        asm volatile(
          "global_load_dwordx4 %0, %4, off sc1\n\t"
          "global_load_dwordx4 %1, %5, off sc1\n\t"
          "global_load_dwordx4 %2, %6, off sc1\n\t"
          "global_load_dwordx4 %3, %7, off sc1\n\t"
          "s_waitcnt vmcnt(0)"
          : "=&v"(v0), "=&v"(v1), "=&v"(v2), "=&v"(v3)
          : "v"(a[0]), "v"(a[1]), "v"(a[2]), "v"(a[3])
          : "memory");
        if (v0.x >= need && v1.x >= need && v2.x >= need && v3.x >= need) break;
        if (++spins > (1L << 16)) break;
      }
    }
    __syncthreads();
    #pragma unroll
    for (int q = 0; q < 4; q++) {
      int s = tid + q * 512;
      int gq = s >> 5, bb = s & 31;
      u32x4 vv = (q == 0) ? v0 : (q == 1) ? v1 : (q == 2) ? v2 : v3;
      uint32_t* d = (uint32_t*)(&hs[bb][gq * 4]);
      d[0] = vv.y; d[1] = vv.z;
    }
    __syncthreads();
    f32x4 acc0 = {0,0,0,0}, acc1 = acc0;
    #pragma unroll
    for (int kk = 0; kk < 8; kk++) {
      int k0 = kk * 32 + lkb;
      bfrag ah0, ah1;
      ah0.q = *(const uint4*)(&hs[lrow][k0]);
      ah1.q = *(const uint4*)(&hs[16 + lrow][k0]);
      acc0 = __builtin_amdgcn_mfma_f32_16x16x32_bf16(ah0.v, wh[kk].v, acc0, 0, 0, 0);
      acc1 = __builtin_amdgcn_mfma_f32_16x16x32_bf16(ah1.v, wh[kk].v, acc1, 0, 0, 0);
    }
    {
      int colT = lane & 15, rb = (lane >> 4) * 4;
      #pragma unroll
      for (int rr = 0; rr < 4; rr++) {
        ts[(rb + rr) * 18 + colT]      = acc0[rr];
        ts[(16 + rb + rr) * 18 + colT] = acc1[rr];
      }
    }
    int e2 = (lane & 1) * 2;
    float gv00 = ts[beta * 18 + 0 + e2],  gv01 = ts[beta * 18 + 1 + e2];
    float gv10 = ts[beta * 18 + 4 + e2],  gv11 = ts[beta * 18 + 5 + e2];
    float gv20 = ts[beta * 18 + 8 + e2],  gv21 = ts[beta * 18 + 9 + e2];
    float gv30 = ts[beta * 18 + 12 + e2], gv31 = ts[beta * 18 + 13 + e2];
    {
      int upd = (t < len) ? 1 : 0;
      float gi0 = gv00 + g0.a[0], gi1 = gv01 + g0.a[1];
      float gf0 = gv10 + g1.a[0], gf1 = gv11 + g1.a[1];
      float gg0 = gv20 + g2.a[0], gg1 = gv21 + g2.a[1];
      float go0 = gv30 + g3.a[0], go1 = gv31 + g3.a[1];
      float c2a = sig_fast(gf0) * c0 + sig_fast(gi0) * tanh_fast(gg0);
      float c2b = sig_fast(gf1) * c1 + sig_fast(gi1) * tanh_fast(gg1);
      float h2a = sig_fast(go0) * tanh_fast(c2a);
      float h2b = sig_fast(go1) * tanh_fast(c2b);
      c0 = upd ? c2a : c0;
      c1 = upd ? c2b : c1;
      uint32_t hiw;
      if (upd) {
        uint16_t ha = f2bf(h2a), hbb = f2bf(h2b);
        hiw = (uint32_t)ha | ((uint32_t)hbb << 16);
      } else hiw = hprev_hi;
      hprev_hi = hiw;
      uint32_t hiw_p = __shfl_down(hiw, 1);
      if ((lane & 1) == 0) {
        uint32_t* gout = grd + ((size_t)(((i + 1) & 1) * 64 + g64) * NB + beta) * 4;
        u32x4 pv;
        pv.x = (uint32_t)(i + 1); pv.y = hiw; pv.z = hiw_p; pv.w = 0u;
        asm volatile("global_store_dwordx4 %0, %1, off sc1"
                     :: "v"((unsigned long long)(uintptr_t)gout), "v"(pv) : "memory");
      }
    }
    // ---- tail: strip-gated g prefetch for step i+1 (off critical path) ----
    if (i + 1 < NS) {
      int tn = dir ? (NS - 2 - i) : (i + 1);
      int msn = tn >> 1;
      if (!(ready_mask & (1u << msn))) {
        long sp = 0;
        while (ld_agent_int(&ctrl[64 + dir * 32 + msn]) < 64) {
          __builtin_amdgcn_s_sleep(2);
          if (++sp > (1L << 20)) break;
        }
        ready_mask |= 1u << msn;
      }
      const float* gptr = gb + ((size_t)tn * NB + beta) * NG + u0 + wave * 4 + (lane & 1) * 2;
      g0.v = lda_f2(gptr);       g1.v = lda_f2(gptr + 256);
      g2.v = lda_f2(gptr + 512); g3.v = lda_f2(gptr + 768);
    }
  }

  // ================= final epilogue: FC + BN + ReLU + log_softmax ==========
  #pragma unroll
  for (int q = 0; q < 8; q++) {            // poll all parity-0 granules, both dirs
    int s = tid + q * 512;                 // 0..4095
    int d_ = s >> 11, r2 = s & 2047;
    const uint32_t* ga = gr + ((size_t)d_ * 2 * 2048 + r2) * 4;
    long sp = 0;
    while (ld_agent_u32(ga) < (uint32_t)NS) {
      __builtin_amdgcn_s_sleep(1);
      if (++sp > (1L << 20)) break;
    }
  }
  __syncthreads();                         // hs/tscr dead; alias hid over smem
  float* hid = (float*)smem_;              // [32][513]
  for (int idx = tid; idx < NB * 512; idx += 512) {
    int bb = idx >> 9, k = idx & 511;
    int bsrc = 2 * (bb & 15) + (k >> 8);
    int hcol = k & 255;
    int dirn = (bb < 16) ? 0 : 1;
    const uint32_t* g = gr + ((size_t)dirn * 2 * 64 * NB + (size_t)(hcol >> 2) * NB + bsrc) * 4;
    uint32_t w = ld_agent_u32(g + 1 + ((hcol >> 1) & 1));
    hid[bb * 513 + k] = bf2f((uint16_t)(w >> ((hcol & 1) * 16)));
  }
  __syncthreads();
  int o = blockIdx.x * 8 + wave;           // 16 blocks x 8 waves = 128 units
  int b = lane >> 1, half = lane & 1;
  const float* wrow = fc_w + (size_t)o * 512 + half * 256;
  const float* hrow = &hid[b * 513 + half * 256];
  float part = 0.0f;
  #pragma unroll 8
  for (int j = 0; j < 256; j++) part += wrow[j] * hrow[j];
  part += __shfl_xor(part, 1);
  float y = part + fc_b[o];
  float s2 = y;
  #pragma unroll
  for (int off = 2; off < 64; off <<= 1) s2 += __shfl_xor(s2, off);
  float mu = s2 * (1.0f / 32.0f);
  float d = y - mu;
  float v2 = d * d;
  #pragma unroll
  for (int off = 2; off < 64; off <<= 1) v2 += __shfl_xor(v2, off);
  float var = v2 * (1.0f / 32.0f);
  float gm = gamma_[o], be = beta_[o];
  float inv = 1.0f / sqrtf(var + 1e-5f);
  float yy = fmaxf(gm * (y - mu) * inv + be, 0.0f);
  float m = yy;
  #pragma unroll
  for (int off = 2; off < 64; off <<= 1) m = fmaxf(m, __shfl_xor(m, off));
  float e = expf(yy - m);
  float se = e;
  #pragma unroll
  for (int off = 2; off < 64; off <<= 1) se += __shfl_xor(se, off);
  float lse = m + logf(se);
  if (half == 0) outp[b * NOUT + o] = yy - lse;
}

extern "C" void kernel_launch(void* const* d_in, const int* in_sizes, int n_in,
                              void* d_out, int out_size, void* d_ws, size_t ws_size,
                              hipStream_t stream) {
  (void)in_sizes; (void)n_in; (void)out_size; (void)ws_size;
  const int*   x      = (const int*)  d_in[0];
  const void*  xmask  =               d_in[1];
  const float* xfeat  = (const float*)d_in[2];
  const int*   slen   = (const int*)  d_in[3];
  const float* emb    = (const float*)d_in[6];
  const float* attn_w = (const float*)d_in[7];
  const float* wih_f  = (const float*)d_in[9];
  const float* whh_f  = (const float*)d_in[10];
  const float* bih_f  = (const float*)d_in[11];
  const float* bhh_f  = (const float*)d_in[12];
  const float* wih_b  = (const float*)d_in[13];
  const float* whh_b  = (const float*)d_in[14];
  const float* bih_b  = (const float*)d_in[15];
  const float* bhh_b  = (const float*)d_in[16];
  const float* fc_w   = (const float*)d_in[17];
  const float* fc_b   = (const float*)d_in[18];
  const float* gam    = (const float*)d_in[19];
  const float* bet    = (const float*)d_in[20];

  char* ws = (char*)d_ws;
  int*      ctrl  = (int*)ws;                        // [8..40) detect slots, [64..128) strip tags
  uint32_t* gr    = (uint32_t*)(ws + 4096);          // granules 2dir x 2par x 64 x 32 x 16B (131,072 B)
  uint16_t* Xb    = (uint16_t*)(ws + 135168);        // 2 planes x 1280x320 bf16 (1,638,400 B)
  uint16_t* wihb  = (uint16_t*)(ws + 1773568);       // 4 planes x 1024x320 bf16 (2,621,440 B)
  float*    gbase = (float*)(ws + 4395008);          // 2x1280x1024 f32 (10,485,760 B)

  k_detect<<<32, 256, 0, stream>>>((const uint32_t*)xmask, ctrl, gr);
  k_attn_prep<<<2560, 256, 0, stream>>>(x, xmask, xfeat, slen, emb, attn_w, Xb, ctrl,
                                        wih_f, wih_b, wihb);
  k_fused<<<336, 512, 0, stream>>>(Xb, wihb, bih_f, bhh_f, bih_b, bhh_b,
                                   whh_f, whh_b, slen, gbase, gr, ctrl,
                                   fc_w, fc_b, gam, bet, (float*)d_out);
}

// Round 15
// 243.890 us; speedup vs baseline: 1.2012x; 1.2012x over previous
//
#include <hip/hip_runtime.h>
#include <stdint.h>

#define NB 32
#define NS 40
#define NT 60
#define NH 256
#define NF 64
#define NDIN 320
#define NG 1024
#define NSB 1280
#define NOUT 128

typedef __bf16 bf16x8 __attribute__((ext_vector_type(8)));
typedef float f32x4 __attribute__((ext_vector_type(4)));
typedef uint32_t u32x4 __attribute__((ext_vector_type(4)));

union bfrag { bf16x8 v; uint16_t u[8]; uint4 q; uint64_t d[2]; };
union f2arr { float2 v; float a[2]; };

__device__ __forceinline__ uint16_t f2bf(float f) {
  uint32_t u = __float_as_uint(f);
  u += 0x7fffu + ((u >> 16) & 1u);
  return (uint16_t)(u >> 16);
}
__device__ __forceinline__ float bf2f(uint16_t h) {
  return __uint_as_float(((uint32_t)h) << 16);
}
__device__ __forceinline__ float sig_fast(float x) { return 1.0f / (1.0f + __expf(-x)); }
__device__ __forceinline__ float tanh_fast(float x) {
  x = fminf(fmaxf(x, -15.0f), 15.0f);
  float t = __expf(2.0f * x);
  return (t - 1.0f) / (t + 1.0f);
}
__device__ __forceinline__ uint32_t ld_agent_u32(const uint32_t* p) {
  return __hip_atomic_load(p, __ATOMIC_RELAXED, __HIP_MEMORY_SCOPE_AGENT);
}

// ------- detect (32 blocks): classify mask dtype into per-block slots AND
// zero the granule region (replaces hipMemsetAsync).
__global__ __launch_bounds__(256) void k_detect(const uint32_t* __restrict__ xm,
                                                int* __restrict__ flags,
                                                uint32_t* __restrict__ gr) {
  int bid = blockIdx.x, tid = threadIdx.x;
  {
    int gidx = bid * 256 + tid;
    u32x4 z = {0, 0, 0, 0};
    asm volatile("global_store_dwordx4 %0, %1, off sc1"
                 :: "v"((unsigned long long)(uintptr_t)(gr + (size_t)gidx * 4)), "v"(z)
                 : "memory");
  }
  __shared__ int s_notint, s_notflt;
  if (tid == 0) { s_notint = 0; s_notflt = 0; }
  __syncthreads();
  int notint = 0, notflt = 0;
  for (int i = bid * 600 + tid; i < (bid + 1) * 600; i += 256) {  // 32*600 = 19200 u32
    uint32_t v = xm[i];
    if (v > 1u) notint = 1;
    if (v != 0u && v != 0x3f800000u) notflt = 1;
  }
  if (notint) atomicOr(&s_notint, 1);
  if (notflt) atomicOr(&s_notflt, 1);
  __syncthreads();
  if (tid == 0) flags[8 + bid] = s_notint | (s_notflt << 1);
}

// ------- merged: blocks [0,1280) attention pooling; [1280,2560) wih prep ----
__global__ __launch_bounds__(256) void k_attn_prep(
    const int* __restrict__ x, const void* __restrict__ xmask,
    const float* __restrict__ xfeat, const int* __restrict__ slen,
    const float* __restrict__ emb, const float* __restrict__ attn_w,
    uint16_t* __restrict__ Xb, const int* __restrict__ flagp,
    const float* __restrict__ wf, const float* __restrict__ wb,
    uint16_t* __restrict__ outw)
{
  int tid = threadIdx.x;
  if (blockIdx.x >= 1280) {              // ---- wih -> hi/lo bf16 planes ----
    const int n = NG * NDIN;
    for (int idx = (blockIdx.x - 1280) * 256 + tid; idx < 2 * n; idx += 1280 * 256) {
      float v = (idx < n) ? wf[idx] : wb[idx - n];
      uint16_t hi = f2bf(v);
      outw[idx] = hi;
      outw[2 * n + idx] = f2bf(v - bf2f(hi));
    }
    return;
  }
  int bs = blockIdx.x;
  int b = bs / NS, s = bs % NS;
  uint16_t* Xh = Xb + (size_t)(s * NB + b) * NDIN;
  uint16_t* Xl = Xh + (size_t)NSB * NDIN;
  int len = slen[b];
  if (s >= len) {
    for (int i = tid; i < NDIN; i += 256) { Xh[i] = 0; Xl[i] = 0; }
    return;
  }
  __shared__ __attribute__((aligned(16))) float sw[NH];
  __shared__ float salpha[NT];
  __shared__ int sidx[NT];
  __shared__ unsigned char svalid[NT];
  __shared__ __attribute__((aligned(16))) uint16_t es[NT][NH];
  sw[tid] = attn_w[tid];
  int nv = 0;
  #pragma unroll
  for (int q = 0; q < 32; q++) nv |= flagp[8 + q];
  int flag = (!(nv & 1)) ? 0 : ((!(nv & 2)) ? 2 : 1);
  if (tid < NT) {
    int mi = bs * NT + tid;
    sidx[tid] = x[mi];
    int mv;
    if (flag == 1)      mv = ((const unsigned char*)xmask)[mi];
    else if (flag == 2) mv = (((const float*)xmask)[mi] != 0.0f) ? 1 : 0;
    else                mv = ((const int*)xmask)[mi];
    svalid[tid] = (mv == 0) ? 1 : 0;
  }
  __syncthreads();
  int wave = tid >> 6, lane = tid & 63;
  for (int t = wave; t < NT; t += 4) {
    float d = 0.0f;
    if (svalid[t]) {
      const float* er = emb + (size_t)sidx[t] * NH;
      float4 e4 = ((const float4*)er)[lane];
      float4 w4 = ((const float4*)sw)[lane];
      uint16_t* ed = &es[t][lane * 4];
      ed[0] = f2bf(e4.x); ed[1] = f2bf(e4.y); ed[2] = f2bf(e4.z); ed[3] = f2bf(e4.w);
      d = e4.x * w4.x + e4.y * w4.y + e4.z * w4.z + e4.w * w4.w;
      #pragma unroll
      for (int o = 32; o > 0; o >>= 1) d += __shfl_down(d, o);
    }
    if (lane == 0) salpha[t] = d;
  }
  __syncthreads();
  if (tid < 64) {                        // wave-parallel softmax over <=60 tokens
    int valid = (tid < NT) && svalid[tid];
    float v = valid ? salpha[tid] : -1e30f;
    float m = v;
    #pragma unroll
    for (int o = 32; o > 0; o >>= 1) m = fmaxf(m, __shfl_xor(m, o));
    float e = valid ? expf(v - m) : 0.0f;
    float ssum = e;
    #pragma unroll
    for (int o = 32; o > 0; o >>= 1) ssum += __shfl_xor(ssum, o);
    if (tid < NT) salpha[tid] = e / ssum;
  }
  __syncthreads();
  float acc = 0.0f;
  for (int t = 0; t < NT; t++) {
    float a = salpha[t];
    if (a != 0.0f) acc += a * bf2f(es[t][tid]);
  }
  {
    uint16_t hi = f2bf(acc);
    Xh[tid] = hi; Xl[tid] = f2bf(acc - bf2f(hi));
  }
  if (tid < NF) {
    float fa = 0.0f;
    const float* fp = xfeat + (size_t)bs * NT * NF + tid;
    for (int t = 0; t < NT; t++) if (svalid[t]) fa += fp[t * NF];
    uint16_t hi = f2bf(fa);
    Xh[NH + tid] = hi; Xl[NH + tid] = f2bf(fa - bf2f(hi));
  }
}

// ------- gbase = X @ wih^T + bih + bhh, hi/lo split operands ----------------
// Separate kernel on purpose (R14 lesson): plain stores stay L2-resident.
__global__ __launch_bounds__(512) void k_gbase(
    const uint16_t* __restrict__ Xb, const uint16_t* __restrict__ wihb,
    const float* __restrict__ bih_f, const float* __restrict__ bhh_f,
    const float* __restrict__ bih_b, const float* __restrict__ bhh_b,
    float* __restrict__ gbase)
{
  const int n = NG * NDIN;
  int wave = threadIdx.x >> 6, lane = threadIdx.x & 63;
  int job = blockIdx.x * 8 + wave;
  int dir = job / 1280;
  int r = job % 1280;
  int nt = r % 64, ms = r / 64;
  int m0 = ms * 64;
  const uint16_t* Wh = wihb + (size_t)dir * n;
  const uint16_t* Wl = Wh + (size_t)2 * n;
  const uint16_t* Ah = Xb;
  const uint16_t* Al = Xb + (size_t)NSB * NDIN;
  int lrow = lane & 15, lk = (lane >> 4) * 8;
  f32x4 acc0 = {0,0,0,0}, acc1 = acc0, acc2 = acc0, acc3 = acc0;
  for (int kk = 0; kk < 10; kk++) {
    int k0 = kk * 32 + lk;
    bfrag bh, bl, ah0, ah1, ah2, ah3, al0, al1, al2, al3;
    bh.q = *(const uint4*)(Wh + (size_t)(nt * 16 + lrow) * NDIN + k0);
    bl.q = *(const uint4*)(Wl + (size_t)(nt * 16 + lrow) * NDIN + k0);
    ah0.q = *(const uint4*)(Ah + (size_t)(m0 +  0 + lrow) * NDIN + k0);
    ah1.q = *(const uint4*)(Ah + (size_t)(m0 + 16 + lrow) * NDIN + k0);
    ah2.q = *(const uint4*)(Ah + (size_t)(m0 + 32 + lrow) * NDIN + k0);
    ah3.q = *(const uint4*)(Ah + (size_t)(m0 + 48 + lrow) * NDIN + k0);
    al0.q = *(const uint4*)(Al + (size_t)(m0 +  0 + lrow) * NDIN + k0);
    al1.q = *(const uint4*)(Al + (size_t)(m0 + 16 + lrow) * NDIN + k0);
    al2.q = *(const uint4*)(Al + (size_t)(m0 + 32 + lrow) * NDIN + k0);
    al3.q = *(const uint4*)(Al + (size_t)(m0 + 48 + lrow) * NDIN + k0);
    acc0 = __builtin_amdgcn_mfma_f32_16x16x32_bf16(ah0.v, bh.v, acc0, 0, 0, 0);
    acc0 = __builtin_amdgcn_mfma_f32_16x16x32_bf16(ah0.v, bl.v, acc0, 0, 0, 0);
    acc0 = __builtin_amdgcn_mfma_f32_16x16x32_bf16(al0.v, bh.v, acc0, 0, 0, 0);
    acc1 = __builtin_amdgcn_mfma_f32_16x16x32_bf16(ah1.v, bh.v, acc1, 0, 0, 0);
    acc1 = __builtin_amdgcn_mfma_f32_16x16x32_bf16(ah1.v, bl.v, acc1, 0, 0, 0);
    acc1 = __builtin_amdgcn_mfma_f32_16x16x32_bf16(al1.v, bh.v, acc1, 0, 0, 0);
    acc2 = __builtin_amdgcn_mfma_f32_16x16x32_bf16(ah2.v, bh.v, acc2, 0, 0, 0);
    acc2 = __builtin_amdgcn_mfma_f32_16x16x32_bf16(ah2.v, bl.v, acc2, 0, 0, 0);
    acc2 = __builtin_amdgcn_mfma_f32_16x16x32_bf16(al2.v, bh.v, acc2, 0, 0, 0);
    acc3 = __builtin_amdgcn_mfma_f32_16x16x32_bf16(ah3.v, bh.v, acc3, 0, 0, 0);
    acc3 = __builtin_amdgcn_mfma_f32_16x16x32_bf16(ah3.v, bl.v, acc3, 0, 0, 0);
    acc3 = __builtin_amdgcn_mfma_f32_16x16x32_bf16(al3.v, bh.v, acc3, 0, 0, 0);
  }
  int col = nt * 16 + lrow;
  float bias = dir ? (bih_b[col] + bhh_b[col]) : (bih_f[col] + bhh_f[col]);
  float* gb = gbase + (size_t)dir * NSB * NG;
  int rb = (lane >> 4) * 4;
  #pragma unroll
  for (int rr = 0; rr < 4; rr++) {
    gb[(size_t)(m0 +  0 + rb + rr) * NG + col] = acc0[rr] + bias;
    gb[(size_t)(m0 + 16 + rb + rr) * NG + col] = acc1[rr] + bias;
    gb[(size_t)(m0 + 32 + rb + rr) * NG + col] = acc2[rr] + bias;
    gb[(size_t)(m0 + 48 + rb + rr) * NG + col] = acc3[rr] + bias;
  }
}

// ---- persistent bidirectional LSTM (R12/R13 step loop verbatim) + fused ----
// final epilogue (R14-proven): after the recurrence, poll parity-0 granules
// to tag>=NS, decode into LDS (aliased over dead hs/tscr), then wave-per-unit
// FC + BN + ReLU + log_softmax. Saves the k_final launch + drain boundary.
__global__ __launch_bounds__(512, 2) void k_lstm(
    const float* __restrict__ whh_f_, const float* __restrict__ whh_b_,
    const float* __restrict__ gbase, const int* __restrict__ slen,
    uint32_t* __restrict__ gr,
    const float* __restrict__ fc_w, const float* __restrict__ fc_b,
    const float* __restrict__ gamma_, const float* __restrict__ beta_,
    float* __restrict__ outp)
{
  __shared__ __attribute__((aligned(16))) char smem_[65664];
  uint16_t (*hs)[264] = (uint16_t(*)[264])smem_;                 // 16896 B
  volatile float* tsb = (volatile float*)(smem_ + 16896);        // 8 x 576 f32

  int wg = blockIdx.x;
  int dir = wg >> 3, p = wg & 7;
  int u0 = p * 32;
  int tid = threadIdx.x, wave = tid >> 6, lane = tid & 63;
  int lrow = lane & 15, lkb = (lane >> 4) * 8;
  const float* Wr = dir ? whh_b_ : whh_f_;
  const float* gb = gbase + (size_t)dir * NSB * NG;
  uint32_t* grd = gr + (size_t)dir * 2 * 64 * NB * 4;   // [par][g64][batch]{4xu32}

  bfrag wh[8];
  {
    int wr = (lrow >> 2) * 256 + u0 + wave * 4 + (lrow & 3);
    const float* wrow = Wr + (size_t)wr * NH;
    #pragma unroll
    for (int kk = 0; kk < 8; kk++) {
      int k0 = kk * 32 + lkb;
      bfrag th;
      #pragma unroll
      for (int e = 0; e < 8; e++) th.u[e] = f2bf(wrow[k0 + e]);
      wh[kk] = th;
    }
  }
  int beta = lane >> 1;
  int g64 = p * 8 + wave;
  int len = slen[beta];
  uint32_t hprev_hi = 0;
  float c0 = 0.0f, c1 = 0.0f;

  unsigned long long sa[2][4];
  #pragma unroll
  for (int par = 0; par < 2; par++) {
    const uint32_t* gpar = grd + (size_t)par * 64 * NB * 4;
    #pragma unroll
    for (int q = 0; q < 4; q++)
      sa[par][q] = (unsigned long long)(uintptr_t)(gpar + (size_t)(tid + q * 512) * 4);
  }

  for (int i = 0; i < NS; i++) {
    int t = dir ? (NS - 1 - i) : i;
    // ---- g prefetch (plain loads, L2-cacheable, overlap the granule wait) --
    const float* gptr = gb + ((size_t)t * NB + beta) * NG + u0 + wave * 4 + (lane & 1) * 2;
    f2arr g0, g1, g2, g3;
    g0.v = *(const float2*)(gptr);
    g1.v = *(const float2*)(gptr + 256);
    g2.v = *(const float2*)(gptr + 512);
    g3.v = *(const float2*)(gptr + 768);
    // ---- tagged-granule fetch: 4 x 16B sc1, retry until tags >= i ----
    u32x4 v0, v1, v2, v3;
    {
      const unsigned long long* a = sa[i & 1];
      uint32_t need = (uint32_t)i;
      long spins = 0;
      for (;;) {
        asm volatile(
          "global_load_dwordx4 %0, %4, off sc1\n\t"
          "global_load_dwordx4 %1, %5, off sc1\n\t"
          "global_load_dwordx4 %2, %6, off sc1\n\t"
          "global_load_dwordx4 %3, %7, off sc1\n\t"
          "s_waitcnt vmcnt(0)"
          : "=&v"(v0), "=&v"(v1), "=&v"(v2), "=&v"(v3)
          : "v"(a[0]), "v"(a[1]), "v"(a[2]), "v"(a[3])
          : "memory");
        if (v0.x >= need && v1.x >= need && v2.x >= need && v3.x >= need) break;
        if (++spins > (1L << 16)) break;
      }
    }
    __syncthreads();
    #pragma unroll
    for (int q = 0; q < 4; q++) {
      int s = tid + q * 512;
      int gq = s >> 5, bb = s & 31;
      u32x4 vv = (q == 0) ? v0 : (q == 1) ? v1 : (q == 2) ? v2 : v3;
      uint32_t* d = (uint32_t*)(&hs[bb][gq * 4]);
      d[0] = vv.y; d[1] = vv.z;
    }
    __syncthreads();
    f32x4 acc0 = {0,0,0,0}, acc1 = acc0;
    #pragma unroll
    for (int kk = 0; kk < 8; kk++) {
      int k0 = kk * 32 + lkb;
      bfrag ah0, ah1;
      ah0.q = *(const uint4*)(&hs[lrow][k0]);
      ah1.q = *(const uint4*)(&hs[16 + lrow][k0]);
      acc0 = __builtin_amdgcn_mfma_f32_16x16x32_bf16(ah0.v, wh[kk].v, acc0, 0, 0, 0);
      acc1 = __builtin_amdgcn_mfma_f32_16x16x32_bf16(ah1.v, wh[kk].v, acc1, 0, 0, 0);
    }
    volatile float* ts = tsb + wave * 576;
    {
      int colT = lane & 15, rb = (lane >> 4) * 4;
      #pragma unroll
      for (int rr = 0; rr < 4; rr++) {
        ts[(rb + rr) * 18 + colT]      = acc0[rr];
        ts[(16 + rb + rr) * 18 + colT] = acc1[rr];
      }
    }
    int e2 = (lane & 1) * 2;
    float gv00 = ts[beta * 18 + 0 + e2],  gv01 = ts[beta * 18 + 1 + e2];
    float gv10 = ts[beta * 18 + 4 + e2],  gv11 = ts[beta * 18 + 5 + e2];
    float gv20 = ts[beta * 18 + 8 + e2],  gv21 = ts[beta * 18 + 9 + e2];
    float gv30 = ts[beta * 18 + 12 + e2], gv31 = ts[beta * 18 + 13 + e2];
    {
      int upd = (t < len) ? 1 : 0;
      float gi0 = gv00 + g0.a[0], gi1 = gv01 + g0.a[1];
      float gf0 = gv10 + g1.a[0], gf1 = gv11 + g1.a[1];
      float gg0 = gv20 + g2.a[0], gg1 = gv21 + g2.a[1];
      float go0 = gv30 + g3.a[0], go1 = gv31 + g3.a[1];
      float c2a = sig_fast(gf0) * c0 + sig_fast(gi0) * tanh_fast(gg0);
      float c2b = sig_fast(gf1) * c1 + sig_fast(gi1) * tanh_fast(gg1);
      float h2a = sig_fast(go0) * tanh_fast(c2a);
      float h2b = sig_fast(go1) * tanh_fast(c2b);
      c0 = upd ? c2a : c0;
      c1 = upd ? c2b : c1;
      uint32_t hiw;
      if (upd) {
        uint16_t ha = f2bf(h2a), hbb = f2bf(h2b);
        hiw = (uint32_t)ha | ((uint32_t)hbb << 16);
      } else hiw = hprev_hi;
      hprev_hi = hiw;
      uint32_t hiw_p = __shfl_down(hiw, 1);
      if ((lane & 1) == 0) {
        uint32_t* gout = grd + ((size_t)(((i + 1) & 1) * 64 + g64) * NB + beta) * 4;
        u32x4 pv;
        pv.x = (uint32_t)(i + 1); pv.y = hiw; pv.z = hiw_p; pv.w = 0u;
        asm volatile("global_store_dwordx4 %0, %1, off sc1"
                     :: "v"((unsigned long long)(uintptr_t)gout), "v"(pv) : "memory");
      }
    }
  }

  // ================= final epilogue: FC + BN + ReLU + log_softmax ==========
  #pragma unroll
  for (int q = 0; q < 8; q++) {            // poll all parity-0 granules, both dirs
    int s = tid + q * 512;                 // 0..4095
    int d_ = s >> 11, r2 = s & 2047;
    const uint32_t* ga = gr + ((size_t)d_ * 2 * 2048 + r2) * 4;
    long sp = 0;
    while (ld_agent_u32(ga) < (uint32_t)NS) {
      __builtin_amdgcn_s_sleep(1);
      if (++sp > (1L << 20)) break;
    }
  }
  __syncthreads();                         // hs/tscr dead; alias hid over smem
  float* hid = (float*)smem_;              // [32][513]
  for (int idx = tid; idx < NB * 512; idx += 512) {
    int bb = idx >> 9, k = idx & 511;
    int bsrc = 2 * (bb & 15) + (k >> 8);
    int hcol = k & 255;
    int dirn = (bb < 16) ? 0 : 1;
    const uint32_t* g = gr + ((size_t)dirn * 2 * 64 * NB + (size_t)(hcol >> 2) * NB + bsrc) * 4;
    uint32_t w = ld_agent_u32(g + 1 + ((hcol >> 1) & 1));
    hid[bb * 513 + k] = bf2f((uint16_t)(w >> ((hcol & 1) * 16)));
  }
  __syncthreads();
  int o = blockIdx.x * 8 + wave;           // 16 blocks x 8 waves = 128 units
  int b = lane >> 1, half = lane & 1;
  const float* wrow = fc_w + (size_t)o * 512 + half * 256;
  const float* hrow = &hid[b * 513 + half * 256];
  float part = 0.0f;
  #pragma unroll 8
  for (int j = 0; j < 256; j++) part += wrow[j] * hrow[j];
  part += __shfl_xor(part, 1);
  float y = part + fc_b[o];
  float s2 = y;
  #pragma unroll
  for (int off = 2; off < 64; off <<= 1) s2 += __shfl_xor(s2, off);
  float mu = s2 * (1.0f / 32.0f);
  float d = y - mu;
  float v2 = d * d;
  #pragma unroll
  for (int off = 2; off < 64; off <<= 1) v2 += __shfl_xor(v2, off);
  float var = v2 * (1.0f / 32.0f);
  float gm = gamma_[o], be = beta_[o];
  float inv = 1.0f / sqrtf(var + 1e-5f);
  float yy = fmaxf(gm * (y - mu) * inv + be, 0.0f);
  float m = yy;
  #pragma unroll
  for (int off = 2; off < 64; off <<= 1) m = fmaxf(m, __shfl_xor(m, off));
  float e = expf(yy - m);
  float se = e;
  #pragma unroll
  for (int off = 2; off < 64; off <<= 1) se += __shfl_xor(se, off);
  float lse = m + logf(se);
  if (half == 0) outp[b * NOUT + o] = yy - lse;
}

extern "C" void kernel_launch(void* const* d_in, const int* in_sizes, int n_in,
                              void* d_out, int out_size, void* d_ws, size_t ws_size,
                              hipStream_t stream) {
  (void)in_sizes; (void)n_in; (void)out_size; (void)ws_size;
  const int*   x      = (const int*)  d_in[0];
  const void*  xmask  =               d_in[1];
  const float* xfeat  = (const float*)d_in[2];
  const int*   slen   = (const int*)  d_in[3];
  const float* emb    = (const float*)d_in[6];
  const float* attn_w = (const float*)d_in[7];
  const float* wih_f  = (const float*)d_in[9];
  const float* whh_f  = (const float*)d_in[10];
  const float* bih_f  = (const float*)d_in[11];
  const float* bhh_f  = (const float*)d_in[12];
  const float* wih_b  = (const float*)d_in[13];
  const float* whh_b  = (const float*)d_in[14];
  const float* bih_b  = (const float*)d_in[15];
  const float* bhh_b  = (const float*)d_in[16];
  const float* fc_w   = (const float*)d_in[17];
  const float* fc_b   = (const float*)d_in[18];
  const float* gam    = (const float*)d_in[19];
  const float* bet    = (const float*)d_in[20];

  char* ws = (char*)d_ws;
  int*      flags = (int*)ws;                        // slots [8..40): per-block detect
  uint32_t* gr    = (uint32_t*)(ws + 4096);          // granules 2dir x 2par x 64 x 32 x 16B (131,072 B)
  uint16_t* Xb    = (uint16_t*)(ws + 135168);        // 2 planes x 1280x320 bf16 (1,638,400 B)
  uint16_t* wihb  = (uint16_t*)(ws + 1773568);       // 4 planes x 1024x320 bf16 (2,621,440 B)
  float*    gbase = (float*)(ws + 4395008);          // 2x1280x1024 f32 (10,485,760 B)

  k_detect<<<32, 256, 0, stream>>>((const uint32_t*)xmask, flags, gr);
  k_attn_prep<<<2560, 256, 0, stream>>>(x, xmask, xfeat, slen, emb, attn_w, Xb, flags,
                                        wih_f, wih_b, wihb);
  k_gbase<<<320, 512, 0, stream>>>(Xb, wihb, bih_f, bhh_f, bih_b, bhh_b, gbase);
  k_lstm<<<16, 512, 0, stream>>>(whh_f, whh_b, gbase, slen, gr,
                                 fc_w, fc_b, gam, bet, (float*)d_out);
}

// Round 16
// 229.392 us; speedup vs baseline: 1.2771x; 1.0632x over previous
//
#include <hip/hip_runtime.h>
#include <stdint.h>

#define NB 32
#define NS 40
#define NT 60
#define NH 256
#define NF 64
#define NDIN 320
#define NG 1024
#define NSB 1280
#define NOUT 128

typedef __bf16 bf16x8 __attribute__((ext_vector_type(8)));
typedef float f32x4 __attribute__((ext_vector_type(4)));
typedef uint32_t u32x4 __attribute__((ext_vector_type(4)));

union bfrag { bf16x8 v; uint16_t u[8]; uint4 q; uint64_t d[2]; };
union f2arr { float2 v; float a[2]; };

__device__ __forceinline__ uint16_t f2bf(float f) {
  uint32_t u = __float_as_uint(f);
  u += 0x7fffu + ((u >> 16) & 1u);
  return (uint16_t)(u >> 16);
}
__device__ __forceinline__ float bf2f(uint16_t h) {
  return __uint_as_float(((uint32_t)h) << 16);
}
__device__ __forceinline__ float sig_fast(float x) { return 1.0f / (1.0f + __expf(-x)); }
__device__ __forceinline__ float tanh_fast(float x) {
  x = fminf(fmaxf(x, -15.0f), 15.0f);
  float t = __expf(2.0f * x);
  return (t - 1.0f) / (t + 1.0f);
}
__device__ __forceinline__ uint32_t ld_agent_u32(const uint32_t* p) {
  return __hip_atomic_load(p, __ATOMIC_RELAXED, __HIP_MEMORY_SCOPE_AGENT);
}

// ------- detect (32 blocks): classify mask dtype into per-block slots AND
// zero the granule region (replaces hipMemsetAsync).
__global__ __launch_bounds__(256) void k_detect(const uint32_t* __restrict__ xm,
                                                int* __restrict__ flags,
                                                uint32_t* __restrict__ gr) {
  int bid = blockIdx.x, tid = threadIdx.x;
  {
    int gidx = bid * 256 + tid;
    u32x4 z = {0, 0, 0, 0};
    asm volatile("global_store_dwordx4 %0, %1, off sc1"
                 :: "v"((unsigned long long)(uintptr_t)(gr + (size_t)gidx * 4)), "v"(z)
                 : "memory");
  }
  __shared__ int s_notint, s_notflt;
  if (tid == 0) { s_notint = 0; s_notflt = 0; }
  __syncthreads();
  int notint = 0, notflt = 0;
  for (int i = bid * 600 + tid; i < (bid + 1) * 600; i += 256) {  // 32*600 = 19200 u32
    uint32_t v = xm[i];
    if (v > 1u) notint = 1;
    if (v != 0u && v != 0x3f800000u) notflt = 1;
  }
  if (notint) atomicOr(&s_notint, 1);
  if (notflt) atomicOr(&s_notflt, 1);
  __syncthreads();
  if (tid == 0) flags[8 + bid] = s_notint | (s_notflt << 1);
}

// ------- merged: blocks [0,1280) attention pooling; [1280,2560) wih prep ----
__global__ __launch_bounds__(256) void k_attn_prep(
    const int* __restrict__ x, const void* __restrict__ xmask,
    const float* __restrict__ xfeat, const int* __restrict__ slen,
    const float* __restrict__ emb, const float* __restrict__ attn_w,
    uint16_t* __restrict__ Xb, const int* __restrict__ flagp,
    const float* __restrict__ wf, const float* __restrict__ wb,
    uint16_t* __restrict__ outw)
{
  int tid = threadIdx.x;
  if (blockIdx.x >= 1280) {              // ---- wih -> hi/lo bf16 planes ----
    const int n = NG * NDIN;
    for (int idx = (blockIdx.x - 1280) * 256 + tid; idx < 2 * n; idx += 1280 * 256) {
      float v = (idx < n) ? wf[idx] : wb[idx - n];
      uint16_t hi = f2bf(v);
      outw[idx] = hi;
      outw[2 * n + idx] = f2bf(v - bf2f(hi));
    }
    return;
  }
  int bs = blockIdx.x;
  int b = bs / NS, s = bs % NS;
  uint16_t* Xh = Xb + (size_t)(s * NB + b) * NDIN;
  uint16_t* Xl = Xh + (size_t)NSB * NDIN;
  int len = slen[b];
  if (s >= len) {
    for (int i = tid; i < NDIN; i += 256) { Xh[i] = 0; Xl[i] = 0; }
    return;
  }
  __shared__ __attribute__((aligned(16))) float sw[NH];
  __shared__ float salpha[NT];
  __shared__ int sidx[NT];
  __shared__ unsigned char svalid[NT];
  __shared__ __attribute__((aligned(16))) uint16_t es[NT][NH];
  sw[tid] = attn_w[tid];
  int nv = 0;
  #pragma unroll
  for (int q = 0; q < 32; q++) nv |= flagp[8 + q];
  int flag = (!(nv & 1)) ? 0 : ((!(nv & 2)) ? 2 : 1);
  if (tid < NT) {
    int mi = bs * NT + tid;
    sidx[tid] = x[mi];
    int mv;
    if (flag == 1)      mv = ((const unsigned char*)xmask)[mi];
    else if (flag == 2) mv = (((const float*)xmask)[mi] != 0.0f) ? 1 : 0;
    else                mv = ((const int*)xmask)[mi];
    svalid[tid] = (mv == 0) ? 1 : 0;
  }
  __syncthreads();
  int wave = tid >> 6, lane = tid & 63;
  for (int t = wave; t < NT; t += 4) {
    float d = 0.0f;
    if (svalid[t]) {
      const float* er = emb + (size_t)sidx[t] * NH;
      float4 e4 = ((const float4*)er)[lane];
      float4 w4 = ((const float4*)sw)[lane];
      uint16_t* ed = &es[t][lane * 4];
      ed[0] = f2bf(e4.x); ed[1] = f2bf(e4.y); ed[2] = f2bf(e4.z); ed[3] = f2bf(e4.w);
      d = e4.x * w4.x + e4.y * w4.y + e4.z * w4.z + e4.w * w4.w;
      #pragma unroll
      for (int o = 32; o > 0; o >>= 1) d += __shfl_down(d, o);
    }
    if (lane == 0) salpha[t] = d;
  }
  __syncthreads();
  if (tid < 64) {                        // wave-parallel softmax over <=60 tokens
    int valid = (tid < NT) && svalid[tid];
    float v = valid ? salpha[tid] : -1e30f;
    float m = v;
    #pragma unroll
    for (int o = 32; o > 0; o >>= 1) m = fmaxf(m, __shfl_xor(m, o));
    float e = valid ? expf(v - m) : 0.0f;
    float ssum = e;
    #pragma unroll
    for (int o = 32; o > 0; o >>= 1) ssum += __shfl_xor(ssum, o);
    if (tid < NT) salpha[tid] = e / ssum;
  }
  __syncthreads();
  float acc = 0.0f;
  for (int t = 0; t < NT; t++) {
    float a = salpha[t];
    if (a != 0.0f) acc += a * bf2f(es[t][tid]);
  }
  {
    uint16_t hi = f2bf(acc);
    Xh[tid] = hi; Xl[tid] = f2bf(acc - bf2f(hi));
  }
  if (tid < NF) {
    float fa = 0.0f;
    const float* fp = xfeat + (size_t)bs * NT * NF + tid;
    for (int t = 0; t < NT; t++) if (svalid[t]) fa += fp[t * NF];
    uint16_t hi = f2bf(fa);
    Xh[NH + tid] = hi; Xl[NH + tid] = f2bf(fa - bf2f(hi));
  }
}

// ------- gbase = X @ wih^T + bih + bhh, hi/lo split operands ----------------
// Separate kernel on purpose (R14 lesson): plain stores stay L2-resident.
__global__ __launch_bounds__(512) void k_gbase(
    const uint16_t* __restrict__ Xb, const uint16_t* __restrict__ wihb,
    const float* __restrict__ bih_f, const float* __restrict__ bhh_f,
    const float* __restrict__ bih_b, const float* __restrict__ bhh_b,
    float* __restrict__ gbase)
{
  const int n = NG * NDIN;
  int wave = threadIdx.x >> 6, lane = threadIdx.x & 63;
  int job = blockIdx.x * 8 + wave;
  int dir = job / 1280;
  int r = job % 1280;
  int nt = r % 64, ms = r / 64;
  int m0 = ms * 64;
  const uint16_t* Wh = wihb + (size_t)dir * n;
  const uint16_t* Wl = Wh + (size_t)2 * n;
  const uint16_t* Ah = Xb;
  const uint16_t* Al = Xb + (size_t)NSB * NDIN;
  int lrow = lane & 15, lk = (lane >> 4) * 8;
  f32x4 acc0 = {0,0,0,0}, acc1 = acc0, acc2 = acc0, acc3 = acc0;
  for (int kk = 0; kk < 10; kk++) {
    int k0 = kk * 32 + lk;
    bfrag bh, bl, ah0, ah1, ah2, ah3, al0, al1, al2, al3;
    bh.q = *(const uint4*)(Wh + (size_t)(nt * 16 + lrow) * NDIN + k0);
    bl.q = *(const uint4*)(Wl + (size_t)(nt * 16 + lrow) * NDIN + k0);
    ah0.q = *(const uint4*)(Ah + (size_t)(m0 +  0 + lrow) * NDIN + k0);
    ah1.q = *(const uint4*)(Ah + (size_t)(m0 + 16 + lrow) * NDIN + k0);
    ah2.q = *(const uint4*)(Ah + (size_t)(m0 + 32 + lrow) * NDIN + k0);
    ah3.q = *(const uint4*)(Ah + (size_t)(m0 + 48 + lrow) * NDIN + k0);
    al0.q = *(const uint4*)(Al + (size_t)(m0 +  0 + lrow) * NDIN + k0);
    al1.q = *(const uint4*)(Al + (size_t)(m0 + 16 + lrow) * NDIN + k0);
    al2.q = *(const uint4*)(Al + (size_t)(m0 + 32 + lrow) * NDIN + k0);
    al3.q = *(const uint4*)(Al + (size_t)(m0 + 48 + lrow) * NDIN + k0);
    acc0 = __builtin_amdgcn_mfma_f32_16x16x32_bf16(ah0.v, bh.v, acc0, 0, 0, 0);
    acc0 = __builtin_amdgcn_mfma_f32_16x16x32_bf16(ah0.v, bl.v, acc0, 0, 0, 0);
    acc0 = __builtin_amdgcn_mfma_f32_16x16x32_bf16(al0.v, bh.v, acc0, 0, 0, 0);
    acc1 = __builtin_amdgcn_mfma_f32_16x16x32_bf16(ah1.v, bh.v, acc1, 0, 0, 0);
    acc1 = __builtin_amdgcn_mfma_f32_16x16x32_bf16(ah1.v, bl.v, acc1, 0, 0, 0);
    acc1 = __builtin_amdgcn_mfma_f32_16x16x32_bf16(al1.v, bh.v, acc1, 0, 0, 0);
    acc2 = __builtin_amdgcn_mfma_f32_16x16x32_bf16(ah2.v, bh.v, acc2, 0, 0, 0);
    acc2 = __builtin_amdgcn_mfma_f32_16x16x32_bf16(ah2.v, bl.v, acc2, 0, 0, 0);
    acc2 = __builtin_amdgcn_mfma_f32_16x16x32_bf16(al2.v, bh.v, acc2, 0, 0, 0);
    acc3 = __builtin_amdgcn_mfma_f32_16x16x32_bf16(ah3.v, bh.v, acc3, 0, 0, 0);
    acc3 = __builtin_amdgcn_mfma_f32_16x16x32_bf16(ah3.v, bl.v, acc3, 0, 0, 0);
    acc3 = __builtin_amdgcn_mfma_f32_16x16x32_bf16(al3.v, bh.v, acc3, 0, 0, 0);
  }
  int col = nt * 16 + lrow;
  float bias = dir ? (bih_b[col] + bhh_b[col]) : (bih_f[col] + bhh_f[col]);
  float* gb = gbase + (size_t)dir * NSB * NG;
  int rb = (lane >> 4) * 4;
  #pragma unroll
  for (int rr = 0; rr < 4; rr++) {
    gb[(size_t)(m0 +  0 + rb + rr) * NG + col] = acc0[rr] + bias;
    gb[(size_t)(m0 + 16 + rb + rr) * NG + col] = acc1[rr] + bias;
    gb[(size_t)(m0 + 32 + rb + rr) * NG + col] = acc2[rr] + bias;
    gb[(size_t)(m0 + 48 + rb + rr) * NG + col] = acc3[rr] + bias;
  }
}

// ---- persistent bidirectional LSTM + fused final epilogue ------------------
// R16: (a) hs double-buffered -> ONE barrier per step (poll -> scatter ->
// barrier -> MFMA; skew>=2 impossible since poll(i) needs every wave's
// publish(i)); (b) epilogue tag-poll batched in one asm block -- its returned
// words ARE the final h, scattered straight into hid (no re-load).
__global__ __launch_bounds__(512, 2) void k_lstm(
    const float* __restrict__ whh_f_, const float* __restrict__ whh_b_,
    const float* __restrict__ gbase, const int* __restrict__ slen,
    uint32_t* __restrict__ gr,
    const float* __restrict__ fc_w, const float* __restrict__ fc_b,
    const float* __restrict__ gamma_, const float* __restrict__ beta_,
    float* __restrict__ outp)
{
  __shared__ __attribute__((aligned(16))) char smem_[65664];
  uint16_t (*hs0)[264] = (uint16_t(*)[264])smem_;                // 16896 B
  uint16_t (*hs1)[264] = (uint16_t(*)[264])(smem_ + 16896);      // 16896 B
  volatile float* tsb = (volatile float*)(smem_ + 33792);        // 8 x 576 f32

  int wg = blockIdx.x;
  int dir = wg >> 3, p = wg & 7;
  int u0 = p * 32;
  int tid = threadIdx.x, wave = tid >> 6, lane = tid & 63;
  int lrow = lane & 15, lkb = (lane >> 4) * 8;
  const float* Wr = dir ? whh_b_ : whh_f_;
  const float* gb = gbase + (size_t)dir * NSB * NG;
  uint32_t* grd = gr + (size_t)dir * 2 * 64 * NB * 4;   // [par][g64][batch]{4xu32}

  bfrag wh[8];
  {
    int wr = (lrow >> 2) * 256 + u0 + wave * 4 + (lrow & 3);
    const float* wrow = Wr + (size_t)wr * NH;
    #pragma unroll
    for (int kk = 0; kk < 8; kk++) {
      int k0 = kk * 32 + lkb;
      bfrag th;
      #pragma unroll
      for (int e = 0; e < 8; e++) th.u[e] = f2bf(wrow[k0 + e]);
      wh[kk] = th;
    }
  }
  int beta = lane >> 1;
  int g64 = p * 8 + wave;
  int len = slen[beta];
  uint32_t hprev_hi = 0;
  float c0 = 0.0f, c1 = 0.0f;

  unsigned long long sa[2][4];
  #pragma unroll
  for (int par = 0; par < 2; par++) {
    const uint32_t* gpar = grd + (size_t)par * 64 * NB * 4;
    #pragma unroll
    for (int q = 0; q < 4; q++)
      sa[par][q] = (unsigned long long)(uintptr_t)(gpar + (size_t)(tid + q * 512) * 4);
  }

  for (int i = 0; i < NS; i++) {
    int t = dir ? (NS - 1 - i) : i;
    // ---- g prefetch (plain loads, L2-cacheable, overlap the granule wait) --
    const float* gptr = gb + ((size_t)t * NB + beta) * NG + u0 + wave * 4 + (lane & 1) * 2;
    f2arr g0, g1, g2, g3;
    g0.v = *(const float2*)(gptr);
    g1.v = *(const float2*)(gptr + 256);
    g2.v = *(const float2*)(gptr + 512);
    g3.v = *(const float2*)(gptr + 768);
    // ---- tagged-granule fetch: 4 x 16B sc1, retry until tags >= i ----
    u32x4 v0, v1, v2, v3;
    {
      const unsigned long long* a = sa[i & 1];
      uint32_t need = (uint32_t)i;
      long spins = 0;
      for (;;) {
        asm volatile(
          "global_load_dwordx4 %0, %4, off sc1\n\t"
          "global_load_dwordx4 %1, %5, off sc1\n\t"
          "global_load_dwordx4 %2, %6, off sc1\n\t"
          "global_load_dwordx4 %3, %7, off sc1\n\t"
          "s_waitcnt vmcnt(0)"
          : "=&v"(v0), "=&v"(v1), "=&v"(v2), "=&v"(v3)
          : "v"(a[0]), "v"(a[1]), "v"(a[2]), "v"(a[3])
          : "memory");
        if (v0.x >= need && v1.x >= need && v2.x >= need && v3.x >= need) break;
        if (++spins > (1L << 16)) break;
      }
    }
    // ---- scatter into double-buffered hs (no pre-barrier: see header) ----
    uint16_t (*hcur)[264] = (i & 1) ? hs1 : hs0;
    #pragma unroll
    for (int q = 0; q < 4; q++) {
      int s = tid + q * 512;
      int gq = s >> 5, bb = s & 31;
      u32x4 vv = (q == 0) ? v0 : (q == 1) ? v1 : (q == 2) ? v2 : v3;
      uint32_t* d = (uint32_t*)(&hcur[bb][gq * 4]);
      d[0] = vv.y; d[1] = vv.z;
    }
    __syncthreads();                       // ONE barrier per step: hs ready
    f32x4 acc0 = {0,0,0,0}, acc1 = acc0;
    #pragma unroll
    for (int kk = 0; kk < 8; kk++) {
      int k0 = kk * 32 + lkb;
      bfrag ah0, ah1;
      ah0.q = *(const uint4*)(&hcur[lrow][k0]);
      ah1.q = *(const uint4*)(&hcur[16 + lrow][k0]);
      acc0 = __builtin_amdgcn_mfma_f32_16x16x32_bf16(ah0.v, wh[kk].v, acc0, 0, 0, 0);
      acc1 = __builtin_amdgcn_mfma_f32_16x16x32_bf16(ah1.v, wh[kk].v, acc1, 0, 0, 0);
    }
    volatile float* ts = tsb + wave * 576;
    {
      int colT = lane & 15, rb = (lane >> 4) * 4;
      #pragma unroll
      for (int rr = 0; rr < 4; rr++) {
        ts[(rb + rr) * 18 + colT]      = acc0[rr];
        ts[(16 + rb + rr) * 18 + colT] = acc1[rr];
      }
    }
    int e2 = (lane & 1) * 2;
    float gv00 = ts[beta * 18 + 0 + e2],  gv01 = ts[beta * 18 + 1 + e2];
    float gv10 = ts[beta * 18 + 4 + e2],  gv11 = ts[beta * 18 + 5 + e2];
    float gv20 = ts[beta * 18 + 8 + e2],  gv21 = ts[beta * 18 + 9 + e2];
    float gv30 = ts[beta * 18 + 12 + e2], gv31 = ts[beta * 18 + 13 + e2];
    {
      int upd = (t < len) ? 1 : 0;
      float gi0 = gv00 + g0.a[0], gi1 = gv01 + g0.a[1];
      float gf0 = gv10 + g1.a[0], gf1 = gv11 + g1.a[1];
      float gg0 = gv20 + g2.a[0], gg1 = gv21 + g2.a[1];
      float go0 = gv30 + g3.a[0], go1 = gv31 + g3.a[1];
      float c2a = sig_fast(gf0) * c0 + sig_fast(gi0) * tanh_fast(gg0);
      float c2b = sig_fast(gf1) * c1 + sig_fast(gi1) * tanh_fast(gg1);
      float h2a = sig_fast(go0) * tanh_fast(c2a);
      float h2b = sig_fast(go1) * tanh_fast(c2b);
      c0 = upd ? c2a : c0;
      c1 = upd ? c2b : c1;
      uint32_t hiw;
      if (upd) {
        uint16_t ha = f2bf(h2a), hbb = f2bf(h2b);
        hiw = (uint32_t)ha | ((uint32_t)hbb << 16);
      } else hiw = hprev_hi;
      hprev_hi = hiw;
      uint32_t hiw_p = __shfl_down(hiw, 1);
      if ((lane & 1) == 0) {
        uint32_t* gout = grd + ((size_t)(((i + 1) & 1) * 64 + g64) * NB + beta) * 4;
        u32x4 pv;
        pv.x = (uint32_t)(i + 1); pv.y = hiw; pv.z = hiw_p; pv.w = 0u;
        asm volatile("global_store_dwordx4 %0, %1, off sc1"
                     :: "v"((unsigned long long)(uintptr_t)gout), "v"(pv) : "memory");
      }
    }
  }

  // ========== final epilogue: batched poll -> direct hid scatter -> FC =====
  // Thread owns parity-0 granules g = {tid+q*512 | q<4} of dir0 and dir1.
  unsigned long long ea0 = (unsigned long long)(uintptr_t)(gr + (size_t)(tid +    0) * 4);
  unsigned long long ea1 = (unsigned long long)(uintptr_t)(gr + (size_t)(tid +  512) * 4);
  unsigned long long ea2 = (unsigned long long)(uintptr_t)(gr + (size_t)(tid + 1024) * 4);
  unsigned long long ea3 = (unsigned long long)(uintptr_t)(gr + (size_t)(tid + 1536) * 4);
  unsigned long long ea4 = (unsigned long long)(uintptr_t)(gr + (size_t)(4096 + tid +    0) * 4);
  unsigned long long ea5 = (unsigned long long)(uintptr_t)(gr + (size_t)(4096 + tid +  512) * 4);
  unsigned long long ea6 = (unsigned long long)(uintptr_t)(gr + (size_t)(4096 + tid + 1024) * 4);
  unsigned long long ea7 = (unsigned long long)(uintptr_t)(gr + (size_t)(4096 + tid + 1536) * 4);
  u32x4 w0, w1, w2, w3, w4, w5, w6, w7;
  {
    long spins = 0;
    for (;;) {
      asm volatile(
        "global_load_dwordx4 %0, %8, off sc1\n\t"
        "global_load_dwordx4 %1, %9, off sc1\n\t"
        "global_load_dwordx4 %2, %10, off sc1\n\t"
        "global_load_dwordx4 %3, %11, off sc1\n\t"
        "global_load_dwordx4 %4, %12, off sc1\n\t"
        "global_load_dwordx4 %5, %13, off sc1\n\t"
        "global_load_dwordx4 %6, %14, off sc1\n\t"
        "global_load_dwordx4 %7, %15, off sc1\n\t"
        "s_waitcnt vmcnt(0)"
        : "=&v"(w0), "=&v"(w1), "=&v"(w2), "=&v"(w3),
          "=&v"(w4), "=&v"(w5), "=&v"(w6), "=&v"(w7)
        : "v"(ea0), "v"(ea1), "v"(ea2), "v"(ea3),
          "v"(ea4), "v"(ea5), "v"(ea6), "v"(ea7)
        : "memory");
      if (w0.x >= (uint32_t)NS && w1.x >= (uint32_t)NS && w2.x >= (uint32_t)NS &&
          w3.x >= (uint32_t)NS && w4.x >= (uint32_t)NS && w5.x >= (uint32_t)NS &&
          w6.x >= (uint32_t)NS && w7.x >= (uint32_t)NS) break;
      if (++spins > (1L << 20)) break;
    }
  }
  __syncthreads();                         // all waves past hs/tscr reads
  float* hid = (float*)smem_;              // [32][513], aliases hs/tscr
  #pragma unroll
  for (int q = 0; q < 8; q++) {
    int d_ = q >> 2;
    int r2 = tid + (q & 3) * 512;          // parity-0 granule index within dir
    int gq = r2 >> 5, bb = r2 & 31;
    int bb2 = d_ * 16 + (bb >> 1);
    int kb = (bb & 1) * 256 + gq * 4;
    u32x4 vv = (q == 0) ? w0 : (q == 1) ? w1 : (q == 2) ? w2 : (q == 3) ? w3
             : (q == 4) ? w4 : (q == 5) ? w5 : (q == 6) ? w6 : w7;
    float* hd = &hid[bb2 * 513 + kb];
    hd[0] = bf2f((uint16_t)vv.y);
    hd[1] = bf2f((uint16_t)(vv.y >> 16));
    hd[2] = bf2f((uint16_t)vv.z);
    hd[3] = bf2f((uint16_t)(vv.z >> 16));
  }
  __syncthreads();
  int o = blockIdx.x * 8 + wave;           // 16 blocks x 8 waves = 128 units
  int b = lane >> 1, half = lane & 1;
  const float* wrow = fc_w + (size_t)o * 512 + half * 256;
  const float* hrow = &hid[b * 513 + half * 256];
  float part = 0.0f;
  #pragma unroll 8
  for (int j = 0; j < 256; j++) part += wrow[j] * hrow[j];
  part += __shfl_xor(part, 1);
  float y = part + fc_b[o];
  float s2 = y;
  #pragma unroll
  for (int off = 2; off < 64; off <<= 1) s2 += __shfl_xor(s2, off);
  float mu = s2 * (1.0f / 32.0f);
  float d = y - mu;
  float v2 = d * d;
  #pragma unroll
  for (int off = 2; off < 64; off <<= 1) v2 += __shfl_xor(v2, off);
  float var = v2 * (1.0f / 32.0f);
  float gm = gamma_[o], be = beta_[o];
  float inv = 1.0f / sqrtf(var + 1e-5f);
  float yy = fmaxf(gm * (y - mu) * inv + be, 0.0f);
  float m = yy;
  #pragma unroll
  for (int off = 2; off < 64; off <<= 1) m = fmaxf(m, __shfl_xor(m, off));
  float e = expf(yy - m);
  float se = e;
  #pragma unroll
  for (int off = 2; off < 64; off <<= 1) se += __shfl_xor(se, off);
  float lse = m + logf(se);
  if (half == 0) outp[b * NOUT + o] = yy - lse;
}

extern "C" void kernel_launch(void* const* d_in, const int* in_sizes, int n_in,
                              void* d_out, int out_size, void* d_ws, size_t ws_size,
                              hipStream_t stream) {
  (void)in_sizes; (void)n_in; (void)out_size; (void)ws_size;
  const int*   x      = (const int*)  d_in[0];
  const void*  xmask  =               d_in[1];
  const float* xfeat  = (const float*)d_in[2];
  const int*   slen   = (const int*)  d_in[3];
  const float* emb    = (const float*)d_in[6];
  const float* attn_w = (const float*)d_in[7];
  const float* wih_f  = (const float*)d_in[9];
  const float* whh_f  = (const float*)d_in[10];
  const float* bih_f  = (const float*)d_in[11];
  const float* bhh_f  = (const float*)d_in[12];
  const float* wih_b  = (const float*)d_in[13];
  const float* whh_b  = (const float*)d_in[14];
  const float* bih_b  = (const float*)d_in[15];
  const float* bhh_b  = (const float*)d_in[16];
  const float* fc_w   = (const float*)d_in[17];
  const float* fc_b   = (const float*)d_in[18];
  const float* gam    = (const float*)d_in[19];
  const float* bet    = (const float*)d_in[20];

  char* ws = (char*)d_ws;
  int*      flags = (int*)ws;                        // slots [8..40): per-block detect
  uint32_t* gr    = (uint32_t*)(ws + 4096);          // granules 2dir x 2par x 64 x 32 x 16B (131,072 B)
  uint16_t* Xb    = (uint16_t*)(ws + 135168);        // 2 planes x 1280x320 bf16 (1,638,400 B)
  uint16_t* wihb  = (uint16_t*)(ws + 1773568);       // 4 planes x 1024x320 bf16 (2,621,440 B)
  float*    gbase = (float*)(ws + 4395008);          // 2x1280x1024 f32 (10,485,760 B)

  k_detect<<<32, 256, 0, stream>>>((const uint32_t*)xmask, flags, gr);
  k_attn_prep<<<2560, 256, 0, stream>>>(x, xmask, xfeat, slen, emb, attn_w, Xb, flags,
                                        wih_f, wih_b, wihb);
  k_gbase<<<320, 512, 0, stream>>>(Xb, wihb, bih_f, bhh_f, bih_b, bhh_b, gbase);
  k_lstm<<<16, 512, 0, stream>>>(whh_f, whh_b, gbase, slen, gr,
                                 fc_w, fc_b, gam, bet, (float*)d_out);
}

// Round 17
// 222.328 us; speedup vs baseline: 1.3176x; 1.0318x over previous
//
#include <hip/hip_runtime.h>
#include <stdint.h>

#define NB 32
#define NS 40
#define NT 60
#define NH 256
#define NF 64
#define NDIN 320
#define NG 1024
#define NSB 1280
#define NOUT 128

typedef __bf16 bf16x8 __attribute__((ext_vector_type(8)));
typedef float f32x4 __attribute__((ext_vector_type(4)));
typedef uint32_t u32x4 __attribute__((ext_vector_type(4)));

union bfrag { bf16x8 v; uint16_t u[8]; uint4 q; uint64_t d[2]; };
union f2arr { float2 v; float a[2]; };

__device__ __forceinline__ uint16_t f2bf(float f) {
  uint32_t u = __float_as_uint(f);
  u += 0x7fffu + ((u >> 16) & 1u);
  return (uint16_t)(u >> 16);
}
__device__ __forceinline__ float bf2f(uint16_t h) {
  return __uint_as_float(((uint32_t)h) << 16);
}
__device__ __forceinline__ float sig_fast(float x) { return 1.0f / (1.0f + __expf(-x)); }
__device__ __forceinline__ float tanh_fast(float x) {
  x = fminf(fmaxf(x, -15.0f), 15.0f);
  float t = __expf(2.0f * x);
  return (t - 1.0f) / (t + 1.0f);
}
__device__ __forceinline__ uint32_t ld_agent_u32(const uint32_t* p) {
  return __hip_atomic_load(p, __ATOMIC_RELAXED, __HIP_MEMORY_SCOPE_AGENT);
}

// ------- detect (32 blocks): classify mask dtype into per-block slots AND
// zero the granule region (replaces hipMemsetAsync).
__global__ __launch_bounds__(256) void k_detect(const uint32_t* __restrict__ xm,
                                                int* __restrict__ flags,
                                                uint32_t* __restrict__ gr) {
  int bid = blockIdx.x, tid = threadIdx.x;
  {
    int gidx = bid * 256 + tid;
    u32x4 z = {0, 0, 0, 0};
    asm volatile("global_store_dwordx4 %0, %1, off sc1"
                 :: "v"((unsigned long long)(uintptr_t)(gr + (size_t)gidx * 4)), "v"(z)
                 : "memory");
  }
  __shared__ int s_notint, s_notflt;
  if (tid == 0) { s_notint = 0; s_notflt = 0; }
  __syncthreads();
  int notint = 0, notflt = 0;
  for (int i = bid * 600 + tid; i < (bid + 1) * 600; i += 256) {  // 32*600 = 19200 u32
    uint32_t v = xm[i];
    if (v > 1u) notint = 1;
    if (v != 0u && v != 0x3f800000u) notflt = 1;
  }
  if (notint) atomicOr(&s_notint, 1);
  if (notflt) atomicOr(&s_notflt, 1);
  __syncthreads();
  if (tid == 0) flags[8 + bid] = s_notint | (s_notflt << 1);
}

// ------- merged: blocks [0,1280) attention pooling; [1280,2560) wih prep ----
__global__ __launch_bounds__(256) void k_attn_prep(
    const int* __restrict__ x, const void* __restrict__ xmask,
    const float* __restrict__ xfeat, const int* __restrict__ slen,
    const float* __restrict__ emb, const float* __restrict__ attn_w,
    uint16_t* __restrict__ Xb, const int* __restrict__ flagp,
    const float* __restrict__ wf, const float* __restrict__ wb,
    uint16_t* __restrict__ outw)
{
  int tid = threadIdx.x;
  if (blockIdx.x >= 1280) {              // ---- wih -> hi/lo bf16 planes ----
    const int n = NG * NDIN;
    for (int idx = (blockIdx.x - 1280) * 256 + tid; idx < 2 * n; idx += 1280 * 256) {
      float v = (idx < n) ? wf[idx] : wb[idx - n];
      uint16_t hi = f2bf(v);
      outw[idx] = hi;
      outw[2 * n + idx] = f2bf(v - bf2f(hi));
    }
    return;
  }
  int bs = blockIdx.x;
  int b = bs / NS, s = bs % NS;
  uint16_t* Xh = Xb + (size_t)(s * NB + b) * NDIN;
  uint16_t* Xl = Xh + (size_t)NSB * NDIN;
  int len = slen[b];
  if (s >= len) {
    for (int i = tid; i < NDIN; i += 256) { Xh[i] = 0; Xl[i] = 0; }
    return;
  }
  __shared__ __attribute__((aligned(16))) float sw[NH];
  __shared__ float salpha[NT];
  __shared__ int sidx[NT];
  __shared__ unsigned char svalid[NT];
  __shared__ float feat_s[4][NF];
  __shared__ __attribute__((aligned(16))) uint16_t es[NT][NH];
  sw[tid] = attn_w[tid];
  int nv = 0;
  #pragma unroll
  for (int q = 0; q < 32; q++) nv |= flagp[8 + q];
  int flag = (!(nv & 1)) ? 0 : ((!(nv & 2)) ? 2 : 1);
  if (tid < NT) {
    int mi = bs * NT + tid;
    sidx[tid] = x[mi];
    int mv;
    if (flag == 1)      mv = ((const unsigned char*)xmask)[mi];
    else if (flag == 2) mv = (((const float*)xmask)[mi] != 0.0f) ? 1 : 0;
    else                mv = ((const int*)xmask)[mi];
    svalid[tid] = (mv == 0) ? 1 : 0;
  }
  __syncthreads();
  int wave = tid >> 6, lane = tid & 63;
  // 2 tokens per wave-iteration: wave w covers t = 2w,2w+1 (mod 8); NT even
  {
    float4 w4 = ((const float4*)sw)[lane];
    for (int t2 = wave * 2; t2 < NT; t2 += 8) {
      int tA = t2, tB = t2 + 1;
      int vA = svalid[tA], vB = svalid[tB];
      float dA = 0.0f, dB = 0.0f;
      if (vA) {
        const float* er = emb + (size_t)sidx[tA] * NH;
        float4 e4 = ((const float4*)er)[lane];
        uint16_t* ed = &es[tA][lane * 4];
        ed[0] = f2bf(e4.x); ed[1] = f2bf(e4.y); ed[2] = f2bf(e4.z); ed[3] = f2bf(e4.w);
        dA = e4.x * w4.x + e4.y * w4.y + e4.z * w4.z + e4.w * w4.w;
      }
      if (vB) {
        const float* er = emb + (size_t)sidx[tB] * NH;
        float4 e4 = ((const float4*)er)[lane];
        uint16_t* ed = &es[tB][lane * 4];
        ed[0] = f2bf(e4.x); ed[1] = f2bf(e4.y); ed[2] = f2bf(e4.z); ed[3] = f2bf(e4.w);
        dB = e4.x * w4.x + e4.y * w4.y + e4.z * w4.z + e4.w * w4.w;
      }
      #pragma unroll
      for (int o = 32; o > 0; o >>= 1) {
        dA += __shfl_down(dA, o);
        dB += __shfl_down(dB, o);
      }
      if (lane == 0) { salpha[tA] = dA; salpha[tB] = dB; }
    }
  }
  // feat_part partials: all 256 threads (4 t-chunks x 64 features)
  {
    int f = tid & 63, ch = tid >> 6;
    float fa = 0.0f;
    const float* fp = xfeat + (size_t)bs * NT * NF + f;
    int t0 = ch * 15, t1 = t0 + 15;
    for (int t = t0; t < t1; t++) if (svalid[t]) fa += fp[t * NF];
    feat_s[ch][f] = fa;
  }
  __syncthreads();
  if (tid < 64) {                        // wave-parallel softmax over <=60 tokens
    int valid = (tid < NT) && svalid[tid];
    float v = valid ? salpha[tid] : -1e30f;
    float m = v;
    #pragma unroll
    for (int o = 32; o > 0; o >>= 1) m = fmaxf(m, __shfl_xor(m, o));
    float e = valid ? expf(v - m) : 0.0f;
    float ssum = e;
    #pragma unroll
    for (int o = 32; o > 0; o >>= 1) ssum += __shfl_xor(ssum, o);
    if (tid < NT) salpha[tid] = e / ssum;
  }
  __syncthreads();
  float acc = 0.0f;
  for (int t = 0; t < NT; t++) {
    float a = salpha[t];
    if (a != 0.0f) acc += a * bf2f(es[t][tid]);
  }
  {
    uint16_t hi = f2bf(acc);
    Xh[tid] = hi; Xl[tid] = f2bf(acc - bf2f(hi));
  }
  if (tid < NF) {
    float fa = feat_s[0][tid] + feat_s[1][tid] + feat_s[2][tid] + feat_s[3][tid];
    uint16_t hi = f2bf(fa);
    Xh[NH + tid] = hi; Xl[NH + tid] = f2bf(fa - bf2f(hi));
  }
}

// ------- gbase = X @ wih^T + bih + bhh, hi/lo split operands ----------------
// Separate kernel on purpose (R14 lesson): plain stores stay L2-resident.
__global__ __launch_bounds__(512) void k_gbase(
    const uint16_t* __restrict__ Xb, const uint16_t* __restrict__ wihb,
    const float* __restrict__ bih_f, const float* __restrict__ bhh_f,
    const float* __restrict__ bih_b, const float* __restrict__ bhh_b,
    float* __restrict__ gbase)
{
  const int n = NG * NDIN;
  int wave = threadIdx.x >> 6, lane = threadIdx.x & 63;
  int job = blockIdx.x * 8 + wave;
  int dir = job / 1280;
  int r = job % 1280;
  int nt = r % 64, ms = r / 64;
  int m0 = ms * 64;
  const uint16_t* Wh = wihb + (size_t)dir * n;
  const uint16_t* Wl = Wh + (size_t)2 * n;
  const uint16_t* Ah = Xb;
  const uint16_t* Al = Xb + (size_t)NSB * NDIN;
  int lrow = lane & 15, lk = (lane >> 4) * 8;
  f32x4 acc0 = {0,0,0,0}, acc1 = acc0, acc2 = acc0, acc3 = acc0;
  for (int kk = 0; kk < 10; kk++) {
    int k0 = kk * 32 + lk;
    bfrag bh, bl, ah0, ah1, ah2, ah3, al0, al1, al2, al3;
    bh.q = *(const uint4*)(Wh + (size_t)(nt * 16 + lrow) * NDIN + k0);
    bl.q = *(const uint4*)(Wl + (size_t)(nt * 16 + lrow) * NDIN + k0);
    ah0.q = *(const uint4*)(Ah + (size_t)(m0 +  0 + lrow) * NDIN + k0);
    ah1.q = *(const uint4*)(Ah + (size_t)(m0 + 16 + lrow) * NDIN + k0);
    ah2.q = *(const uint4*)(Ah + (size_t)(m0 + 32 + lrow) * NDIN + k0);
    ah3.q = *(const uint4*)(Ah + (size_t)(m0 + 48 + lrow) * NDIN + k0);
    al0.q = *(const uint4*)(Al + (size_t)(m0 +  0 + lrow) * NDIN + k0);
    al1.q = *(const uint4*)(Al + (size_t)(m0 + 16 + lrow) * NDIN + k0);
    al2.q = *(const uint4*)(Al + (size_t)(m0 + 32 + lrow) * NDIN + k0);
    al3.q = *(const uint4*)(Al + (size_t)(m0 + 48 + lrow) * NDIN + k0);
    acc0 = __builtin_amdgcn_mfma_f32_16x16x32_bf16(ah0.v, bh.v, acc0, 0, 0, 0);
    acc0 = __builtin_amdgcn_mfma_f32_16x16x32_bf16(ah0.v, bl.v, acc0, 0, 0, 0);
    acc0 = __builtin_amdgcn_mfma_f32_16x16x32_bf16(al0.v, bh.v, acc0, 0, 0, 0);
    acc1 = __builtin_amdgcn_mfma_f32_16x16x32_bf16(ah1.v, bh.v, acc1, 0, 0, 0);
    acc1 = __builtin_amdgcn_mfma_f32_16x16x32_bf16(ah1.v, bl.v, acc1, 0, 0, 0);
    acc1 = __builtin_amdgcn_mfma_f32_16x16x32_bf16(al1.v, bh.v, acc1, 0, 0, 0);
    acc2 = __builtin_amdgcn_mfma_f32_16x16x32_bf16(ah2.v, bh.v, acc2, 0, 0, 0);
    acc2 = __builtin_amdgcn_mfma_f32_16x16x32_bf16(ah2.v, bl.v, acc2, 0, 0, 0);
    acc2 = __builtin_amdgcn_mfma_f32_16x16x32_bf16(al2.v, bh.v, acc2, 0, 0, 0);
    acc3 = __builtin_amdgcn_mfma_f32_16x16x32_bf16(ah3.v, bh.v, acc3, 0, 0, 0);
    acc3 = __builtin_amdgcn_mfma_f32_16x16x32_bf16(ah3.v, bl.v, acc3, 0, 0, 0);
    acc3 = __builtin_amdgcn_mfma_f32_16x16x32_bf16(al3.v, bh.v, acc3, 0, 0, 0);
  }
  int col = nt * 16 + lrow;
  float bias = dir ? (bih_b[col] + bhh_b[col]) : (bih_f[col] + bhh_f[col]);
  float* gb = gbase + (size_t)dir * NSB * NG;
  int rb = (lane >> 4) * 4;
  #pragma unroll
  for (int rr = 0; rr < 4; rr++) {
    gb[(size_t)(m0 +  0 + rb + rr) * NG + col] = acc0[rr] + bias;
    gb[(size_t)(m0 + 16 + rb + rr) * NG + col] = acc1[rr] + bias;
    gb[(size_t)(m0 + 32 + rb + rr) * NG + col] = acc2[rr] + bias;
    gb[(size_t)(m0 + 48 + rb + rr) * NG + col] = acc3[rr] + bias;
  }
}

// ---- persistent bidirectional LSTM + fused final epilogue (R16 verbatim) ---
__global__ __launch_bounds__(512, 2) void k_lstm(
    const float* __restrict__ whh_f_, const float* __restrict__ whh_b_,
    const float* __restrict__ gbase, const int* __restrict__ slen,
    uint32_t* __restrict__ gr,
    const float* __restrict__ fc_w, const float* __restrict__ fc_b,
    const float* __restrict__ gamma_, const float* __restrict__ beta_,
    float* __restrict__ outp)
{
  __shared__ __attribute__((aligned(16))) char smem_[65664];
  uint16_t (*hs0)[264] = (uint16_t(*)[264])smem_;                // 16896 B
  uint16_t (*hs1)[264] = (uint16_t(*)[264])(smem_ + 16896);      // 16896 B
  volatile float* tsb = (volatile float*)(smem_ + 33792);        // 8 x 576 f32

  int wg = blockIdx.x;
  int dir = wg >> 3, p = wg & 7;
  int u0 = p * 32;
  int tid = threadIdx.x, wave = tid >> 6, lane = tid & 63;
  int lrow = lane & 15, lkb = (lane >> 4) * 8;
  const float* Wr = dir ? whh_b_ : whh_f_;
  const float* gb = gbase + (size_t)dir * NSB * NG;
  uint32_t* grd = gr + (size_t)dir * 2 * 64 * NB * 4;   // [par][g64][batch]{4xu32}

  bfrag wh[8];
  {
    int wr = (lrow >> 2) * 256 + u0 + wave * 4 + (lrow & 3);
    const float* wrow = Wr + (size_t)wr * NH;
    #pragma unroll
    for (int kk = 0; kk < 8; kk++) {
      int k0 = kk * 32 + lkb;
      bfrag th;
      #pragma unroll
      for (int e = 0; e < 8; e++) th.u[e] = f2bf(wrow[k0 + e]);
      wh[kk] = th;
    }
  }
  int beta = lane >> 1;
  int g64 = p * 8 + wave;
  int len = slen[beta];
  uint32_t hprev_hi = 0;
  float c0 = 0.0f, c1 = 0.0f;

  unsigned long long sa[2][4];
  #pragma unroll
  for (int par = 0; par < 2; par++) {
    const uint32_t* gpar = grd + (size_t)par * 64 * NB * 4;
    #pragma unroll
    for (int q = 0; q < 4; q++)
      sa[par][q] = (unsigned long long)(uintptr_t)(gpar + (size_t)(tid + q * 512) * 4);
  }

  for (int i = 0; i < NS; i++) {
    int t = dir ? (NS - 1 - i) : i;
    // ---- g prefetch (plain loads, L2-cacheable, overlap the granule wait) --
    const float* gptr = gb + ((size_t)t * NB + beta) * NG + u0 + wave * 4 + (lane & 1) * 2;
    f2arr g0, g1, g2, g3;
    g0.v = *(const float2*)(gptr);
    g1.v = *(const float2*)(gptr + 256);
    g2.v = *(const float2*)(gptr + 512);
    g3.v = *(const float2*)(gptr + 768);
    // ---- tagged-granule fetch: 4 x 16B sc1, retry until tags >= i ----
    u32x4 v0, v1, v2, v3;
    {
      const unsigned long long* a = sa[i & 1];
      uint32_t need = (uint32_t)i;
      long spins = 0;
      for (;;) {
        asm volatile(
          "global_load_dwordx4 %0, %4, off sc1\n\t"
          "global_load_dwordx4 %1, %5, off sc1\n\t"
          "global_load_dwordx4 %2, %6, off sc1\n\t"
          "global_load_dwordx4 %3, %7, off sc1\n\t"
          "s_waitcnt vmcnt(0)"
          : "=&v"(v0), "=&v"(v1), "=&v"(v2), "=&v"(v3)
          : "v"(a[0]), "v"(a[1]), "v"(a[2]), "v"(a[3])
          : "memory");
        if (v0.x >= need && v1.x >= need && v2.x >= need && v3.x >= need) break;
        if (++spins > (1L << 16)) break;
      }
    }
    // ---- scatter into double-buffered hs (no pre-barrier) ----
    uint16_t (*hcur)[264] = (i & 1) ? hs1 : hs0;
    #pragma unroll
    for (int q = 0; q < 4; q++) {
      int s = tid + q * 512;
      int gq = s >> 5, bb = s & 31;
      u32x4 vv = (q == 0) ? v0 : (q == 1) ? v1 : (q == 2) ? v2 : v3;
      uint32_t* d = (uint32_t*)(&hcur[bb][gq * 4]);
      d[0] = vv.y; d[1] = vv.z;
    }
    __syncthreads();                       // ONE barrier per step: hs ready
    f32x4 acc0 = {0,0,0,0}, acc1 = acc0;
    #pragma unroll
    for (int kk = 0; kk < 8; kk++) {
      int k0 = kk * 32 + lkb;
      bfrag ah0, ah1;
      ah0.q = *(const uint4*)(&hcur[lrow][k0]);
      ah1.q = *(const uint4*)(&hcur[16 + lrow][k0]);
      acc0 = __builtin_amdgcn_mfma_f32_16x16x32_bf16(ah0.v, wh[kk].v, acc0, 0, 0, 0);
      acc1 = __builtin_amdgcn_mfma_f32_16x16x32_bf16(ah1.v, wh[kk].v, acc1, 0, 0, 0);
    }
    volatile float* ts = tsb + wave * 576;
    {
      int colT = lane & 15, rb = (lane >> 4) * 4;
      #pragma unroll
      for (int rr = 0; rr < 4; rr++) {
        ts[(rb + rr) * 18 + colT]      = acc0[rr];
        ts[(16 + rb + rr) * 18 + colT] = acc1[rr];
      }
    }
    int e2 = (lane & 1) * 2;
    float gv00 = ts[beta * 18 + 0 + e2],  gv01 = ts[beta * 18 + 1 + e2];
    float gv10 = ts[beta * 18 + 4 + e2],  gv11 = ts[beta * 18 + 5 + e2];
    float gv20 = ts[beta * 18 + 8 + e2],  gv21 = ts[beta * 18 + 9 + e2];
    float gv30 = ts[beta * 18 + 12 + e2], gv31 = ts[beta * 18 + 13 + e2];
    {
      int upd = (t < len) ? 1 : 0;
      float gi0 = gv00 + g0.a[0], gi1 = gv01 + g0.a[1];
      float gf0 = gv10 + g1.a[0], gf1 = gv11 + g1.a[1];
      float gg0 = gv20 + g2.a[0], gg1 = gv21 + g2.a[1];
      float go0 = gv30 + g3.a[0], go1 = gv31 + g3.a[1];
      float c2a = sig_fast(gf0) * c0 + sig_fast(gi0) * tanh_fast(gg0);
      float c2b = sig_fast(gf1) * c1 + sig_fast(gi1) * tanh_fast(gg1);
      float h2a = sig_fast(go0) * tanh_fast(c2a);
      float h2b = sig_fast(go1) * tanh_fast(c2b);
      c0 = upd ? c2a : c0;
      c1 = upd ? c2b : c1;
      uint32_t hiw;
      if (upd) {
        uint16_t ha = f2bf(h2a), hbb = f2bf(h2b);
        hiw = (uint32_t)ha | ((uint32_t)hbb << 16);
      } else hiw = hprev_hi;
      hprev_hi = hiw;
      uint32_t hiw_p = __shfl_down(hiw, 1);
      if ((lane & 1) == 0) {
        uint32_t* gout = grd + ((size_t)(((i + 1) & 1) * 64 + g64) * NB + beta) * 4;
        u32x4 pv;
        pv.x = (uint32_t)(i + 1); pv.y = hiw; pv.z = hiw_p; pv.w = 0u;
        asm volatile("global_store_dwordx4 %0, %1, off sc1"
                     :: "v"((unsigned long long)(uintptr_t)gout), "v"(pv) : "memory");
      }
    }
  }

  // ========== final epilogue: batched poll -> direct hid scatter -> FC =====
  unsigned long long ea0 = (unsigned long long)(uintptr_t)(gr + (size_t)(tid +    0) * 4);
  unsigned long long ea1 = (unsigned long long)(uintptr_t)(gr + (size_t)(tid +  512) * 4);
  unsigned long long ea2 = (unsigned long long)(uintptr_t)(gr + (size_t)(tid + 1024) * 4);
  unsigned long long ea3 = (unsigned long long)(uintptr_t)(gr + (size_t)(tid + 1536) * 4);
  unsigned long long ea4 = (unsigned long long)(uintptr_t)(gr + (size_t)(4096 + tid +    0) * 4);
  unsigned long long ea5 = (unsigned long long)(uintptr_t)(gr + (size_t)(4096 + tid +  512) * 4);
  unsigned long long ea6 = (unsigned long long)(uintptr_t)(gr + (size_t)(4096 + tid + 1024) * 4);
  unsigned long long ea7 = (unsigned long long)(uintptr_t)(gr + (size_t)(4096 + tid + 1536) * 4);
  u32x4 w0, w1, w2, w3, w4, w5, w6, w7;
  {
    long spins = 0;
    for (;;) {
      asm volatile(
        "global_load_dwordx4 %0, %8, off sc1\n\t"
        "global_load_dwordx4 %1, %9, off sc1\n\t"
        "global_load_dwordx4 %2, %10, off sc1\n\t"
        "global_load_dwordx4 %3, %11, off sc1\n\t"
        "global_load_dwordx4 %4, %12, off sc1\n\t"
        "global_load_dwordx4 %5, %13, off sc1\n\t"
        "global_load_dwordx4 %6, %14, off sc1\n\t"
        "global_load_dwordx4 %7, %15, off sc1\n\t"
        "s_waitcnt vmcnt(0)"
        : "=&v"(w0), "=&v"(w1), "=&v"(w2), "=&v"(w3),
          "=&v"(w4), "=&v"(w5), "=&v"(w6), "=&v"(w7)
        : "v"(ea0), "v"(ea1), "v"(ea2), "v"(ea3),
          "v"(ea4), "v"(ea5), "v"(ea6), "v"(ea7)
        : "memory");
      if (w0.x >= (uint32_t)NS && w1.x >= (uint32_t)NS && w2.x >= (uint32_t)NS &&
          w3.x >= (uint32_t)NS && w4.x >= (uint32_t)NS && w5.x >= (uint32_t)NS &&
          w6.x >= (uint32_t)NS && w7.x >= (uint32_t)NS) break;
      if (++spins > (1L << 20)) break;
    }
  }
  __syncthreads();                         // all waves past hs/tscr reads
  float* hid = (float*)smem_;              // [32][513], aliases hs/tscr
  #pragma unroll
  for (int q = 0; q < 8; q++) {
    int d_ = q >> 2;
    int r2 = tid + (q & 3) * 512;          // parity-0 granule index within dir
    int gq = r2 >> 5, bb = r2 & 31;
    int bb2 = d_ * 16 + (bb >> 1);
    int kb = (bb & 1) * 256 + gq * 4;
    u32x4 vv = (q == 0) ? w0 : (q == 1) ? w1 : (q == 2) ? w2 : (q == 3) ? w3
             : (q == 4) ? w4 : (q == 5) ? w5 : (q == 6) ? w6 : w7;
    float* hd = &hid[bb2 * 513 + kb];
    hd[0] = bf2f((uint16_t)vv.y);
    hd[1] = bf2f((uint16_t)(vv.y >> 16));
    hd[2] = bf2f((uint16_t)vv.z);
    hd[3] = bf2f((uint16_t)(vv.z >> 16));
  }
  __syncthreads();
  int o = blockIdx.x * 8 + wave;           // 16 blocks x 8 waves = 128 units
  int b = lane >> 1, half = lane & 1;
  const float* wrow = fc_w + (size_t)o * 512 + half * 256;
  const float* hrow = &hid[b * 513 + half * 256];
  float part = 0.0f;
  #pragma unroll 8
  for (int j = 0; j < 256; j++) part += wrow[j] * hrow[j];
  part += __shfl_xor(part, 1);
  float y = part + fc_b[o];
  float s2 = y;
  #pragma unroll
  for (int off = 2; off < 64; off <<= 1) s2 += __shfl_xor(s2, off);
  float mu = s2 * (1.0f / 32.0f);
  float d = y - mu;
  float v2 = d * d;
  #pragma unroll
  for (int off = 2; off < 64; off <<= 1) v2 += __shfl_xor(v2, off);
  float var = v2 * (1.0f / 32.0f);
  float gm = gamma_[o], be = beta_[o];
  float inv = 1.0f / sqrtf(var + 1e-5f);
  float yy = fmaxf(gm * (y - mu) * inv + be, 0.0f);
  float m = yy;
  #pragma unroll
  for (int off = 2; off < 64; off <<= 1) m = fmaxf(m, __shfl_xor(m, off));
  float e = expf(yy - m);
  float se = e;
  #pragma unroll
  for (int off = 2; off < 64; off <<= 1) se += __shfl_xor(se, off);
  float lse = m + logf(se);
  if (half == 0) outp[b * NOUT + o] = yy - lse;
}

extern "C" void kernel_launch(void* const* d_in, const int* in_sizes, int n_in,
                              void* d_out, int out_size, void* d_ws, size_t ws_size,
                              hipStream_t stream) {
  (void)in_sizes; (void)n_in; (void)out_size; (void)ws_size;
  const int*   x      = (const int*)  d_in[0];
  const void*  xmask  =               d_in[1];
  const float* xfeat  = (const float*)d_in[2];
  const int*   slen   = (const int*)  d_in[3];
  const float* emb    = (const float*)d_in[6];
  const float* attn_w = (const float*)d_in[7];
  const float* wih_f  = (const float*)d_in[9];
  const float* whh_f  = (const float*)d_in[10];
  const float* bih_f  = (const float*)d_in[11];
  const float* bhh_f  = (const float*)d_in[12];
  const float* wih_b  = (const float*)d_in[13];
  const float* whh_b  = (const float*)d_in[14];
  const float* bih_b  = (const float*)d_in[15];
  const float* bhh_b  = (const float*)d_in[16];
  const float* fc_w   = (const float*)d_in[17];
  const float* fc_b   = (const float*)d_in[18];
  const float* gam    = (const float*)d_in[19];
  const float* bet    = (const float*)d_in[20];

  char* ws = (char*)d_ws;
  int*      flags = (int*)ws;                        // slots [8..40): per-block detect
  uint32_t* gr    = (uint32_t*)(ws + 4096);          // granules 2dir x 2par x 64 x 32 x 16B (131,072 B)
  uint16_t* Xb    = (uint16_t*)(ws + 135168);        // 2 planes x 1280x320 bf16 (1,638,400 B)
  uint16_t* wihb  = (uint16_t*)(ws + 1773568);       // 4 planes x 1024x320 bf16 (2,621,440 B)
  float*    gbase = (float*)(ws + 4395008);          // 2x1280x1024 f32 (10,485,760 B)

  k_detect<<<32, 256, 0, stream>>>((const uint32_t*)xmask, flags, gr);
  k_attn_prep<<<2560, 256, 0, stream>>>(x, xmask, xfeat, slen, emb, attn_w, Xb, flags,
                                        wih_f, wih_b, wihb);
  k_gbase<<<320, 512, 0, stream>>>(Xb, wihb, bih_f, bhh_f, bih_b, bhh_b, gbase);
  k_lstm<<<16, 512, 0, stream>>>(whh_f, whh_b, gbase, slen, gr,
                                 fc_w, fc_b, gam, bet, (float*)d_out);
}

// Round 18
// 215.900 us; speedup vs baseline: 1.3569x; 1.0298x over previous
//
#include <hip/hip_runtime.h>
#include <stdint.h>

#define NB 32
#define NS 40
#define NT 60
#define NH 256
#define NF 64
#define NDIN 320
#define NG 1024
#define NSB 1280
#define NOUT 128

typedef __bf16 bf16x8 __attribute__((ext_vector_type(8)));
typedef float f32x4 __attribute__((ext_vector_type(4)));
typedef uint32_t u32x4 __attribute__((ext_vector_type(4)));

union bfrag { bf16x8 v; uint16_t u[8]; uint4 q; uint64_t d[2]; };
union f2arr { float2 v; float a[2]; };

__device__ __forceinline__ uint16_t f2bf(float f) {
  uint32_t u = __float_as_uint(f);
  u += 0x7fffu + ((u >> 16) & 1u);
  return (uint16_t)(u >> 16);
}
__device__ __forceinline__ float bf2f(uint16_t h) {
  return __uint_as_float(((uint32_t)h) << 16);
}
__device__ __forceinline__ float sig_fast(float x) { return 1.0f / (1.0f + __expf(-x)); }
__device__ __forceinline__ float tanh_fast(float x) {
  x = fminf(fmaxf(x, -15.0f), 15.0f);
  float t = __expf(2.0f * x);
  return (t - 1.0f) / (t + 1.0f);
}
__device__ __forceinline__ uint32_t ld_agent_u32(const uint32_t* p) {
  return __hip_atomic_load(p, __ATOMIC_RELAXED, __HIP_MEMORY_SCOPE_AGENT);
}

// ------- detect (32 blocks): classify mask dtype into per-block slots AND
// zero the granule region (replaces hipMemsetAsync).
__global__ __launch_bounds__(256) void k_detect(const uint32_t* __restrict__ xm,
                                                int* __restrict__ flags,
                                                uint32_t* __restrict__ gr) {
  int bid = blockIdx.x, tid = threadIdx.x;
  {
    int gidx = bid * 256 + tid;
    u32x4 z = {0, 0, 0, 0};
    asm volatile("global_store_dwordx4 %0, %1, off sc1"
                 :: "v"((unsigned long long)(uintptr_t)(gr + (size_t)gidx * 4)), "v"(z)
                 : "memory");
  }
  __shared__ int s_notint, s_notflt;
  if (tid == 0) { s_notint = 0; s_notflt = 0; }
  __syncthreads();
  int notint = 0, notflt = 0;
  for (int i = bid * 600 + tid; i < (bid + 1) * 600; i += 256) {  // 32*600 = 19200 u32
    uint32_t v = xm[i];
    if (v > 1u) notint = 1;
    if (v != 0u && v != 0x3f800000u) notflt = 1;
  }
  if (notint) atomicOr(&s_notint, 1);
  if (notflt) atomicOr(&s_notflt, 1);
  __syncthreads();
  if (tid == 0) flags[8 + bid] = s_notint | (s_notflt << 1);
}

// ------- merged: blocks [0,1280) attention pooling; [1280,2560) wih prep ----
__global__ __launch_bounds__(256) void k_attn_prep(
    const int* __restrict__ x, const void* __restrict__ xmask,
    const float* __restrict__ xfeat, const int* __restrict__ slen,
    const float* __restrict__ emb, const float* __restrict__ attn_w,
    uint16_t* __restrict__ Xb, const int* __restrict__ flagp,
    const float* __restrict__ wf, const float* __restrict__ wb,
    uint16_t* __restrict__ outw)
{
  int tid = threadIdx.x;
  if (blockIdx.x >= 1280) {              // ---- wih -> hi/lo bf16 planes ----
    const int n = NG * NDIN;
    for (int idx = (blockIdx.x - 1280) * 256 + tid; idx < 2 * n; idx += 1280 * 256) {
      float v = (idx < n) ? wf[idx] : wb[idx - n];
      uint16_t hi = f2bf(v);
      outw[idx] = hi;
      outw[2 * n + idx] = f2bf(v - bf2f(hi));
    }
    return;
  }
  int bs = blockIdx.x;
  int b = bs / NS, s = bs % NS;
  uint16_t* Xh = Xb + (size_t)(s * NB + b) * NDIN;
  uint16_t* Xl = Xh + (size_t)NSB * NDIN;
  int len = slen[b];
  if (s >= len) {
    for (int i = tid; i < NDIN; i += 256) { Xh[i] = 0; Xl[i] = 0; }
    return;
  }
  __shared__ __attribute__((aligned(16))) float sw[NH];
  __shared__ float salpha[NT];
  __shared__ int sidx[NT];
  __shared__ unsigned char svalid[NT];
  __shared__ float feat_s[4][NF];
  __shared__ __attribute__((aligned(16))) uint16_t es[NT][NH];
  sw[tid] = attn_w[tid];
  int nv = 0;
  #pragma unroll
  for (int q = 0; q < 32; q++) nv |= flagp[8 + q];
  int flag = (!(nv & 1)) ? 0 : ((!(nv & 2)) ? 2 : 1);
  if (tid < NT) {
    int mi = bs * NT + tid;
    sidx[tid] = x[mi];
    int mv;
    if (flag == 1)      mv = ((const unsigned char*)xmask)[mi];
    else if (flag == 2) mv = (((const float*)xmask)[mi] != 0.0f) ? 1 : 0;
    else                mv = ((const int*)xmask)[mi];
    svalid[tid] = (mv == 0) ? 1 : 0;
  }
  __syncthreads();
  int wave = tid >> 6, lane = tid & 63;
  // 4 tokens per wave-iteration: wave w covers t = 4w..4w+3 (mod 16)
  {
    float4 w4 = ((const float4*)sw)[lane];
    for (int t2 = wave * 4; t2 < NT; t2 += 16) {
      int tA = t2, tB = t2 + 1, tC = t2 + 2, tD = t2 + 3;
      int vA = svalid[tA], vB = svalid[tB], vC = svalid[tC], vD = svalid[tD];
      float dA = 0.0f, dB = 0.0f, dC = 0.0f, dD = 0.0f;
      if (vA) {
        const float* er = emb + (size_t)sidx[tA] * NH;
        float4 e4 = ((const float4*)er)[lane];
        uint16_t* ed = &es[tA][lane * 4];
        ed[0] = f2bf(e4.x); ed[1] = f2bf(e4.y); ed[2] = f2bf(e4.z); ed[3] = f2bf(e4.w);
        dA = e4.x * w4.x + e4.y * w4.y + e4.z * w4.z + e4.w * w4.w;
      }
      if (vB) {
        const float* er = emb + (size_t)sidx[tB] * NH;
        float4 e4 = ((const float4*)er)[lane];
        uint16_t* ed = &es[tB][lane * 4];
        ed[0] = f2bf(e4.x); ed[1] = f2bf(e4.y); ed[2] = f2bf(e4.z); ed[3] = f2bf(e4.w);
        dB = e4.x * w4.x + e4.y * w4.y + e4.z * w4.z + e4.w * w4.w;
      }
      if (vC) {
        const float* er = emb + (size_t)sidx[tC] * NH;
        float4 e4 = ((const float4*)er)[lane];
        uint16_t* ed = &es[tC][lane * 4];
        ed[0] = f2bf(e4.x); ed[1] = f2bf(e4.y); ed[2] = f2bf(e4.z); ed[3] = f2bf(e4.w);
        dC = e4.x * w4.x + e4.y * w4.y + e4.z * w4.z + e4.w * w4.w;
      }
      if (vD) {
        const float* er = emb + (size_t)sidx[tD] * NH;
        float4 e4 = ((const float4*)er)[lane];
        uint16_t* ed = &es[tD][lane * 4];
        ed[0] = f2bf(e4.x); ed[1] = f2bf(e4.y); ed[2] = f2bf(e4.z); ed[3] = f2bf(e4.w);
        dD = e4.x * w4.x + e4.y * w4.y + e4.z * w4.z + e4.w * w4.w;
      }
      #pragma unroll
      for (int o = 32; o > 0; o >>= 1) {
        dA += __shfl_down(dA, o);
        dB += __shfl_down(dB, o);
        dC += __shfl_down(dC, o);
        dD += __shfl_down(dD, o);
      }
      if (lane == 0) {
        salpha[tA] = dA; salpha[tB] = dB; salpha[tC] = dC; salpha[tD] = dD;
      }
    }
  }
  // feat_part partials: all 256 threads (4 t-chunks x 64 features)
  {
    int f = tid & 63, ch = tid >> 6;
    float fa = 0.0f;
    const float* fp = xfeat + (size_t)bs * NT * NF + f;
    int t0 = ch * 15, t1 = t0 + 15;
    for (int t = t0; t < t1; t++) if (svalid[t]) fa += fp[t * NF];
    feat_s[ch][f] = fa;
  }
  __syncthreads();
  if (tid < 64) {                        // wave-parallel softmax over <=60 tokens
    int valid = (tid < NT) && svalid[tid];
    float v = valid ? salpha[tid] : -1e30f;
    float m = v;
    #pragma unroll
    for (int o = 32; o > 0; o >>= 1) m = fmaxf(m, __shfl_xor(m, o));
    float e = valid ? expf(v - m) : 0.0f;
    float ssum = e;
    #pragma unroll
    for (int o = 32; o > 0; o >>= 1) ssum += __shfl_xor(ssum, o);
    if (tid < NT) salpha[tid] = e / ssum;
  }
  __syncthreads();
  // emb_part: 4-way unrolled (independent accumulators for ILP); NT = 60
  float ac0 = 0.0f, ac1 = 0.0f, ac2 = 0.0f, ac3 = 0.0f;
  for (int t = 0; t < NT; t += 4) {
    float a0 = salpha[t],     a1 = salpha[t + 1];
    float a2 = salpha[t + 2], a3 = salpha[t + 3];
    if (a0 != 0.0f) ac0 += a0 * bf2f(es[t][tid]);
    if (a1 != 0.0f) ac1 += a1 * bf2f(es[t + 1][tid]);
    if (a2 != 0.0f) ac2 += a2 * bf2f(es[t + 2][tid]);
    if (a3 != 0.0f) ac3 += a3 * bf2f(es[t + 3][tid]);
  }
  {
    float acc = (ac0 + ac1) + (ac2 + ac3);
    uint16_t hi = f2bf(acc);
    Xh[tid] = hi; Xl[tid] = f2bf(acc - bf2f(hi));
  }
  if (tid < NF) {
    float fa = feat_s[0][tid] + feat_s[1][tid] + feat_s[2][tid] + feat_s[3][tid];
    uint16_t hi = f2bf(fa);
    Xh[NH + tid] = hi; Xl[NH + tid] = f2bf(fa - bf2f(hi));
  }
}

// ------- gbase = X @ wih^T + bih + bhh, hi/lo split operands ----------------
// Separate kernel on purpose (R14 lesson): plain stores stay L2-resident.
__global__ __launch_bounds__(512) void k_gbase(
    const uint16_t* __restrict__ Xb, const uint16_t* __restrict__ wihb,
    const float* __restrict__ bih_f, const float* __restrict__ bhh_f,
    const float* __restrict__ bih_b, const float* __restrict__ bhh_b,
    float* __restrict__ gbase)
{
  const int n = NG * NDIN;
  int wave = threadIdx.x >> 6, lane = threadIdx.x & 63;
  int job = blockIdx.x * 8 + wave;
  int dir = job / 1280;
  int r = job % 1280;
  int nt = r % 64, ms = r / 64;
  int m0 = ms * 64;
  const uint16_t* Wh = wihb + (size_t)dir * n;
  const uint16_t* Wl = Wh + (size_t)2 * n;
  const uint16_t* Ah = Xb;
  const uint16_t* Al = Xb + (size_t)NSB * NDIN;
  int lrow = lane & 15, lk = (lane >> 4) * 8;
  f32x4 acc0 = {0,0,0,0}, acc1 = acc0, acc2 = acc0, acc3 = acc0;
  for (int kk = 0; kk < 10; kk++) {
    int k0 = kk * 32 + lk;
    bfrag bh, bl, ah0, ah1, ah2, ah3, al0, al1, al2, al3;
    bh.q = *(const uint4*)(Wh + (size_t)(nt * 16 + lrow) * NDIN + k0);
    bl.q = *(const uint4*)(Wl + (size_t)(nt * 16 + lrow) * NDIN + k0);
    ah0.q = *(const uint4*)(Ah + (size_t)(m0 +  0 + lrow) * NDIN + k0);
    ah1.q = *(const uint4*)(Ah + (size_t)(m0 + 16 + lrow) * NDIN + k0);
    ah2.q = *(const uint4*)(Ah + (size_t)(m0 + 32 + lrow) * NDIN + k0);
    ah3.q = *(const uint4*)(Ah + (size_t)(m0 + 48 + lrow) * NDIN + k0);
    al0.q = *(const uint4*)(Al + (size_t)(m0 +  0 + lrow) * NDIN + k0);
    al1.q = *(const uint4*)(Al + (size_t)(m0 + 16 + lrow) * NDIN + k0);
    al2.q = *(const uint4*)(Al + (size_t)(m0 + 32 + lrow) * NDIN + k0);
    al3.q = *(const uint4*)(Al + (size_t)(m0 + 48 + lrow) * NDIN + k0);
    acc0 = __builtin_amdgcn_mfma_f32_16x16x32_bf16(ah0.v, bh.v, acc0, 0, 0, 0);
    acc0 = __builtin_amdgcn_mfma_f32_16x16x32_bf16(ah0.v, bl.v, acc0, 0, 0, 0);
    acc0 = __builtin_amdgcn_mfma_f32_16x16x32_bf16(al0.v, bh.v, acc0, 0, 0, 0);
    acc1 = __builtin_amdgcn_mfma_f32_16x16x32_bf16(ah1.v, bh.v, acc1, 0, 0, 0);
    acc1 = __builtin_amdgcn_mfma_f32_16x16x32_bf16(ah1.v, bl.v, acc1, 0, 0, 0);
    acc1 = __builtin_amdgcn_mfma_f32_16x16x32_bf16(al1.v, bh.v, acc1, 0, 0, 0);
    acc2 = __builtin_amdgcn_mfma_f32_16x16x32_bf16(ah2.v, bh.v, acc2, 0, 0, 0);
    acc2 = __builtin_amdgcn_mfma_f32_16x16x32_bf16(ah2.v, bl.v, acc2, 0, 0, 0);
    acc2 = __builtin_amdgcn_mfma_f32_16x16x32_bf16(al2.v, bh.v, acc2, 0, 0, 0);
    acc3 = __builtin_amdgcn_mfma_f32_16x16x32_bf16(ah3.v, bh.v, acc3, 0, 0, 0);
    acc3 = __builtin_amdgcn_mfma_f32_16x16x32_bf16(ah3.v, bl.v, acc3, 0, 0, 0);
    acc3 = __builtin_amdgcn_mfma_f32_16x16x32_bf16(al3.v, bh.v, acc3, 0, 0, 0);
  }
  int col = nt * 16 + lrow;
  float bias = dir ? (bih_b[col] + bhh_b[col]) : (bih_f[col] + bhh_f[col]);
  float* gb = gbase + (size_t)dir * NSB * NG;
  int rb = (lane >> 4) * 4;
  #pragma unroll
  for (int rr = 0; rr < 4; rr++) {
    gb[(size_t)(m0 +  0 + rb + rr) * NG + col] = acc0[rr] + bias;
    gb[(size_t)(m0 + 16 + rb + rr) * NG + col] = acc1[rr] + bias;
    gb[(size_t)(m0 + 32 + rb + rr) * NG + col] = acc2[rr] + bias;
    gb[(size_t)(m0 + 48 + rb + rr) * NG + col] = acc3[rr] + bias;
  }
}

// ---- persistent bidirectional LSTM + fused final epilogue (R16 verbatim) ---
__global__ __launch_bounds__(512, 2) void k_lstm(
    const float* __restrict__ whh_f_, const float* __restrict__ whh_b_,
    const float* __restrict__ gbase, const int* __restrict__ slen,
    uint32_t* __restrict__ gr,
    const float* __restrict__ fc_w, const float* __restrict__ fc_b,
    const float* __restrict__ gamma_, const float* __restrict__ beta_,
    float* __restrict__ outp)
{
  __shared__ __attribute__((aligned(16))) char smem_[65664];
  uint16_t (*hs0)[264] = (uint16_t(*)[264])smem_;                // 16896 B
  uint16_t (*hs1)[264] = (uint16_t(*)[264])(smem_ + 16896);      // 16896 B
  volatile float* tsb = (volatile float*)(smem_ + 33792);        // 8 x 576 f32

  int wg = blockIdx.x;
  int dir = wg >> 3, p = wg & 7;
  int u0 = p * 32;
  int tid = threadIdx.x, wave = tid >> 6, lane = tid & 63;
  int lrow = lane & 15, lkb = (lane >> 4) * 8;
  const float* Wr = dir ? whh_b_ : whh_f_;
  const float* gb = gbase + (size_t)dir * NSB * NG;
  uint32_t* grd = gr + (size_t)dir * 2 * 64 * NB * 4;   // [par][g64][batch]{4xu32}

  bfrag wh[8];
  {
    int wr = (lrow >> 2) * 256 + u0 + wave * 4 + (lrow & 3);
    const float* wrow = Wr + (size_t)wr * NH;
    #pragma unroll
    for (int kk = 0; kk < 8; kk++) {
      int k0 = kk * 32 + lkb;
      bfrag th;
      #pragma unroll
      for (int e = 0; e < 8; e++) th.u[e] = f2bf(wrow[k0 + e]);
      wh[kk] = th;
    }
  }
  int beta = lane >> 1;
  int g64 = p * 8 + wave;
  int len = slen[beta];
  uint32_t hprev_hi = 0;
  float c0 = 0.0f, c1 = 0.0f;

  unsigned long long sa[2][4];
  #pragma unroll
  for (int par = 0; par < 2; par++) {
    const uint32_t* gpar = grd + (size_t)par * 64 * NB * 4;
    #pragma unroll
    for (int q = 0; q < 4; q++)
      sa[par][q] = (unsigned long long)(uintptr_t)(gpar + (size_t)(tid + q * 512) * 4);
  }

  for (int i = 0; i < NS; i++) {
    int t = dir ? (NS - 1 - i) : i;
    // ---- g prefetch (plain loads, L2-cacheable, overlap the granule wait) --
    const float* gptr = gb + ((size_t)t * NB + beta) * NG + u0 + wave * 4 + (lane & 1) * 2;
    f2arr g0, g1, g2, g3;
    g0.v = *(const float2*)(gptr);
    g1.v = *(const float2*)(gptr + 256);
    g2.v = *(const float2*)(gptr + 512);
    g3.v = *(const float2*)(gptr + 768);
    // ---- tagged-granule fetch: 4 x 16B sc1, retry until tags >= i ----
    u32x4 v0, v1, v2, v3;
    {
      const unsigned long long* a = sa[i & 1];
      uint32_t need = (uint32_t)i;
      long spins = 0;
      for (;;) {
        asm volatile(
          "global_load_dwordx4 %0, %4, off sc1\n\t"
          "global_load_dwordx4 %1, %5, off sc1\n\t"
          "global_load_dwordx4 %2, %6, off sc1\n\t"
          "global_load_dwordx4 %3, %7, off sc1\n\t"
          "s_waitcnt vmcnt(0)"
          : "=&v"(v0), "=&v"(v1), "=&v"(v2), "=&v"(v3)
          : "v"(a[0]), "v"(a[1]), "v"(a[2]), "v"(a[3])
          : "memory");
        if (v0.x >= need && v1.x >= need && v2.x >= need && v3.x >= need) break;
        if (++spins > (1L << 16)) break;
      }
    }
    // ---- scatter into double-buffered hs (no pre-barrier) ----
    uint16_t (*hcur)[264] = (i & 1) ? hs1 : hs0;
    #pragma unroll
    for (int q = 0; q < 4; q++) {
      int s = tid + q * 512;
      int gq = s >> 5, bb = s & 31;
      u32x4 vv = (q == 0) ? v0 : (q == 1) ? v1 : (q == 2) ? v2 : v3;
      uint32_t* d = (uint32_t*)(&hcur[bb][gq * 4]);
      d[0] = vv.y; d[1] = vv.z;
    }
    __syncthreads();                       // ONE barrier per step: hs ready
    f32x4 acc0 = {0,0,0,0}, acc1 = acc0;
    #pragma unroll
    for (int kk = 0; kk < 8; kk++) {
      int k0 = kk * 32 + lkb;
      bfrag ah0, ah1;
      ah0.q = *(const uint4*)(&hcur[lrow][k0]);
      ah1.q = *(const uint4*)(&hcur[16 + lrow][k0]);
      acc0 = __builtin_amdgcn_mfma_f32_16x16x32_bf16(ah0.v, wh[kk].v, acc0, 0, 0, 0);
      acc1 = __builtin_amdgcn_mfma_f32_16x16x32_bf16(ah1.v, wh[kk].v, acc1, 0, 0, 0);
    }
    volatile float* ts = tsb + wave * 576;
    {
      int colT = lane & 15, rb = (lane >> 4) * 4;
      #pragma unroll
      for (int rr = 0; rr < 4; rr++) {
        ts[(rb + rr) * 18 + colT]      = acc0[rr];
        ts[(16 + rb + rr) * 18 + colT] = acc1[rr];
      }
    }
    int e2 = (lane & 1) * 2;
    float gv00 = ts[beta * 18 + 0 + e2],  gv01 = ts[beta * 18 + 1 + e2];
    float gv10 = ts[beta * 18 + 4 + e2],  gv11 = ts[beta * 18 + 5 + e2];
    float gv20 = ts[beta * 18 + 8 + e2],  gv21 = ts[beta * 18 + 9 + e2];
    float gv30 = ts[beta * 18 + 12 + e2], gv31 = ts[beta * 18 + 13 + e2];
    {
      int upd = (t < len) ? 1 : 0;
      float gi0 = gv00 + g0.a[0], gi1 = gv01 + g0.a[1];
      float gf0 = gv10 + g1.a[0], gf1 = gv11 + g1.a[1];
      float gg0 = gv20 + g2.a[0], gg1 = gv21 + g2.a[1];
      float go0 = gv30 + g3.a[0], go1 = gv31 + g3.a[1];
      float c2a = sig_fast(gf0) * c0 + sig_fast(gi0) * tanh_fast(gg0);
      float c2b = sig_fast(gf1) * c1 + sig_fast(gi1) * tanh_fast(gg1);
      float h2a = sig_fast(go0) * tanh_fast(c2a);
      float h2b = sig_fast(go1) * tanh_fast(c2b);
      c0 = upd ? c2a : c0;
      c1 = upd ? c2b : c1;
      uint32_t hiw;
      if (upd) {
        uint16_t ha = f2bf(h2a), hbb = f2bf(h2b);
        hiw = (uint32_t)ha | ((uint32_t)hbb << 16);
      } else hiw = hprev_hi;
      hprev_hi = hiw;
      uint32_t hiw_p = __shfl_down(hiw, 1);
      if ((lane & 1) == 0) {
        uint32_t* gout = grd + ((size_t)(((i + 1) & 1) * 64 + g64) * NB + beta) * 4;
        u32x4 pv;
        pv.x = (uint32_t)(i + 1); pv.y = hiw; pv.z = hiw_p; pv.w = 0u;
        asm volatile("global_store_dwordx4 %0, %1, off sc1"
                     :: "v"((unsigned long long)(uintptr_t)gout), "v"(pv) : "memory");
      }
    }
  }

  // ========== final epilogue: batched poll -> direct hid scatter -> FC =====
  unsigned long long ea0 = (unsigned long long)(uintptr_t)(gr + (size_t)(tid +    0) * 4);
  unsigned long long ea1 = (unsigned long long)(uintptr_t)(gr + (size_t)(tid +  512) * 4);
  unsigned long long ea2 = (unsigned long long)(uintptr_t)(gr + (size_t)(tid + 1024) * 4);
  unsigned long long ea3 = (unsigned long long)(uintptr_t)(gr + (size_t)(tid + 1536) * 4);
  unsigned long long ea4 = (unsigned long long)(uintptr_t)(gr + (size_t)(4096 + tid +    0) * 4);
  unsigned long long ea5 = (unsigned long long)(uintptr_t)(gr + (size_t)(4096 + tid +  512) * 4);
  unsigned long long ea6 = (unsigned long long)(uintptr_t)(gr + (size_t)(4096 + tid + 1024) * 4);
  unsigned long long ea7 = (unsigned long long)(uintptr_t)(gr + (size_t)(4096 + tid + 1536) * 4);
  u32x4 w0, w1, w2, w3, w4, w5, w6, w7;
  {
    long spins = 0;
    for (;;) {
      asm volatile(
        "global_load_dwordx4 %0, %8, off sc1\n\t"
        "global_load_dwordx4 %1, %9, off sc1\n\t"
        "global_load_dwordx4 %2, %10, off sc1\n\t"
        "global_load_dwordx4 %3, %11, off sc1\n\t"
        "global_load_dwordx4 %4, %12, off sc1\n\t"
        "global_load_dwordx4 %5, %13, off sc1\n\t"
        "global_load_dwordx4 %6, %14, off sc1\n\t"
        "global_load_dwordx4 %7, %15, off sc1\n\t"
        "s_waitcnt vmcnt(0)"
        : "=&v"(w0), "=&v"(w1), "=&v"(w2), "=&v"(w3),
          "=&v"(w4), "=&v"(w5), "=&v"(w6), "=&v"(w7)
        : "v"(ea0), "v"(ea1), "v"(ea2), "v"(ea3),
          "v"(ea4), "v"(ea5), "v"(ea6), "v"(ea7)
        : "memory");
      if (w0.x >= (uint32_t)NS && w1.x >= (uint32_t)NS && w2.x >= (uint32_t)NS &&
          w3.x >= (uint32_t)NS && w4.x >= (uint32_t)NS && w5.x >= (uint32_t)NS &&
          w6.x >= (uint32_t)NS && w7.x >= (uint32_t)NS) break;
      if (++spins > (1L << 20)) break;
    }
  }
  __syncthreads();                         // all waves past hs/tscr reads
  float* hid = (float*)smem_;              // [32][513], aliases hs/tscr
  #pragma unroll
  for (int q = 0; q < 8; q++) {
    int d_ = q >> 2;
    int r2 = tid + (q & 3) * 512;          // parity-0 granule index within dir
    int gq = r2 >> 5, bb = r2 & 31;
    int bb2 = d_ * 16 + (bb >> 1);
    int kb = (bb & 1) * 256 + gq * 4;
    u32x4 vv = (q == 0) ? w0 : (q == 1) ? w1 : (q == 2) ? w2 : (q == 3) ? w3
             : (q == 4) ? w4 : (q == 5) ? w5 : (q == 6) ? w6 : w7;
    float* hd = &hid[bb2 * 513 + kb];
    hd[0] = bf2f((uint16_t)vv.y);
    hd[1] = bf2f((uint16_t)(vv.y >> 16));
    hd[2] = bf2f((uint16_t)vv.z);
    hd[3] = bf2f((uint16_t)(vv.z >> 16));
  }
  __syncthreads();
  int o = blockIdx.x * 8 + wave;           // 16 blocks x 8 waves = 128 units
  int b = lane >> 1, half = lane & 1;
  const float* wrow = fc_w + (size_t)o * 512 + half * 256;
  const float* hrow = &hid[b * 513 + half * 256];
  float part = 0.0f;
  #pragma unroll 8
  for (int j = 0; j < 256; j++) part += wrow[j] * hrow[j];
  part += __shfl_xor(part, 1);
  float y = part + fc_b[o];
  float s2 = y;
  #pragma unroll
  for (int off = 2; off < 64; off <<= 1) s2 += __shfl_xor(s2, off);
  float mu = s2 * (1.0f / 32.0f);
  float d = y - mu;
  float v2 = d * d;
  #pragma unroll
  for (int off = 2; off < 64; off <<= 1) v2 += __shfl_xor(v2, off);
  float var = v2 * (1.0f / 32.0f);
  float gm = gamma_[o], be = beta_[o];
  float inv = 1.0f / sqrtf(var + 1e-5f);
  float yy = fmaxf(gm * (y - mu) * inv + be, 0.0f);
  float m = yy;
  #pragma unroll
  for (int off = 2; off < 64; off <<= 1) m = fmaxf(m, __shfl_xor(m, off));
  float e = expf(yy - m);
  float se = e;
  #pragma unroll
  for (int off = 2; off < 64; off <<= 1) se += __shfl_xor(se, off);
  float lse = m + logf(se);
  if (half == 0) outp[b * NOUT + o] = yy - lse;
}

extern "C" void kernel_launch(void* const* d_in, const int* in_sizes, int n_in,
                              void* d_out, int out_size, void* d_ws, size_t ws_size,
                              hipStream_t stream) {
  (void)in_sizes; (void)n_in; (void)out_size; (void)ws_size;
  const int*   x      = (const int*)  d_in[0];
  const void*  xmask  =               d_in[1];
  const float* xfeat  = (const float*)d_in[2];
  const int*   slen   = (const int*)  d_in[3];
  const float* emb    = (const float*)d_in[6];
  const float* attn_w = (const float*)d_in[7];
  const float* wih_f  = (const float*)d_in[9];
  const float* whh_f  = (const float*)d_in[10];
  const float* bih_f  = (const float*)d_in[11];
  const float* bhh_f  = (const float*)d_in[12];
  const float* wih_b  = (const float*)d_in[13];
  const float* whh_b  = (const float*)d_in[14];
  const float* bih_b  = (const float*)d_in[15];
  const float* bhh_b  = (const float*)d_in[16];
  const float* fc_w   = (const float*)d_in[17];
  const float* fc_b   = (const float*)d_in[18];
  const float* gam    = (const float*)d_in[19];
  const float* bet    = (const float*)d_in[20];

  char* ws = (char*)d_ws;
  int*      flags = (int*)ws;                        // slots [8..40): per-block detect
  uint32_t* gr    = (uint32_t*)(ws + 4096);          // granules 2dir x 2par x 64 x 32 x 16B (131,072 B)
  uint16_t* Xb    = (uint16_t*)(ws + 135168);        // 2 planes x 1280x320 bf16 (1,638,400 B)
  uint16_t* wihb  = (uint16_t*)(ws + 1773568);       // 4 planes x 1024x320 bf16 (2,621,440 B)
  float*    gbase = (float*)(ws + 4395008);          // 2x1280x1024 f32 (10,485,760 B)

  k_detect<<<32, 256, 0, stream>>>((const uint32_t*)xmask, flags, gr);
  k_attn_prep<<<2560, 256, 0, stream>>>(x, xmask, xfeat, slen, emb, attn_w, Xb, flags,
                                        wih_f, wih_b, wihb);
  k_gbase<<<320, 512, 0, stream>>>(Xb, wihb, bih_f, bhh_f, bih_b, bhh_b, gbase);
  k_lstm<<<16, 512, 0, stream>>>(whh_f, whh_b, gbase, slen, gr,
                                 fc_w, fc_b, gam, bet, (float*)d_out);
}